// Round 3
// baseline (9037.931 us; speedup 1.0000x reference)
//
#include <hip/hip_runtime.h>
#include <math.h>

// B=16, N=512, D=768, Dh=1536, HEADS=3, keys>=384 masked.
// GEMM core: 128x128 tile, 32x32x16 MFMA, BK=16, DOUBLE-BUFFERED LDS (32KB),
// 2-phase pipeline: stage(t+1) issued before compute(t), one barrier/step.
// bf16x2 hi/lo split (3-pass) for precision-critical GEMMs; AX (adj@inp) runs
// 1-pass bf16 (error /denom~257 -> ~3e-4, under threshold).
// All A-operands async (global_load_lds 16B); B async (bmode=3) or conv-window
// f32 with uint2 LDS writes (bmode=2, ~4-way conflicts vs old 16-32-way).
// Each GEMM launch is template-tagged for per-dispatch rocprof attribution.
//
// Arena (float units), 30539776 (~122.2 MB):
//  S [0,131072): scalars/lists (+QKB bias at 93184)
//  X [131072,+12582912): INPP planes (first half) + XW0f (second half) ->
//    OUT0 f32 -> XCATp planes -> F1P/F2P
//  Z = 12713984 (+17825792):
//   ph1: AXp[0,6.29M) AXW0f[6.29,12.58M) W0P[12.58,13.17M) ADJB[13.17,15.27M)
//   ph2: CONVEp[0,6.29M) CwP[6.29,7.08M) LWPp[7.08,7.67M)
//   ph3: QKp planes[0,8.39M) P f32[8.39,17.83M)
//   ph5: XW1f[0,6.29M) OUTL1p[6.29,12.58M) H1p[0,6.29M after XW1f dead)
//  d_out: ph1 INPTB bf16[0,3.15M); then QKwP[0,4.72M) W1P[4.72,5.9M); final out.

namespace {

constexpr long long O_DEN  = 0;
constexpr long long O_DEN2 = 8192;
constexpr long long O_SUMP = 16384;
constexpr long long O_THR  = 17920;
constexpr long long O_MIDX = 17936;
constexpr long long O_CNT  = 17952;
constexpr long long O_POS  = 17968;
constexpr long long O_T2P  = 18224;
constexpr long long O_NNZC = 19456;
constexpr long long O_NNZJ = 27648;
constexpr long long O_NNZV = 60416;
constexpr long long O_QKB  = 93184;   // 3072 floats

constexpr long long O_X    = 131072;
constexpr long long OZ     = 131072 + 12582912;          // 12713984
constexpr long long TOTAL_FLOATS = OZ + 17825792;        // 30539776

typedef short bf16x8 __attribute__((ext_vector_type(8)));
typedef float f32x4 __attribute__((ext_vector_type(4)));
typedef float f32x16 __attribute__((ext_vector_type(16)));

__global__ void sentinel_kernel(float* out) {
    if (threadIdx.x == 0 && blockIdx.x == 0) out[0] = 1.0e6f;
}

__device__ __forceinline__ unsigned short bf16rne(float f) {
    union { float x; unsigned u; } a; a.x = f;
    return (unsigned short)((a.u + 0x7FFFu + ((a.u >> 16) & 1u)) >> 16);
}

// RNE f32 -> bf16 hi + bf16(residual)
__device__ __forceinline__ void cvt_split(float f, unsigned short& h, unsigned short& l) {
    union { float x; unsigned u; } a; a.x = f;
    unsigned hb = (a.u + 0x7FFFu + ((a.u >> 16) & 1u)) & 0xFFFF0000u;
    h = (unsigned short)(hb >> 16);
    union { unsigned u; float x; } b; b.u = hb;
    float r = f - b.x;
    union { float x; unsigned u; } c; c.x = r;
    l = (unsigned short)((c.u + 0x7FFFu + ((c.u >> 16) & 1u)) >> 16);
}

// async 16B global->LDS (lds dest: wave-uniform base + lane*16)
__device__ __forceinline__ void gl_lds16(const unsigned short* g, unsigned short* l) {
    __builtin_amdgcn_global_load_lds(
        (const __attribute__((address_space(1))) unsigned int*)g,
        (__attribute__((address_space(3))) unsigned int*)l,
        16, 0, 0);
}

// ---------------- f32 -> planes converter ----------------
__global__ void convert_planes_kernel(const float* __restrict__ src, unsigned short* __restrict__ dst,
                                      long long loOff, long long n4) {
    long long idx = (long long)blockIdx.x * 256 + threadIdx.x;
    if (idx >= n4) return;
    float4 v = ((const float4*)src)[idx];
    unsigned short h0,h1,h2,h3,l0,l1,l2,l3;
    cvt_split(v.x,h0,l0); cvt_split(v.y,h1,l1); cvt_split(v.z,h2,l2); cvt_split(v.w,h3,l3);
    uint2 hp, lp;
    hp.x = (unsigned)h0 | ((unsigned)h1 << 16); hp.y = (unsigned)h2 | ((unsigned)h3 << 16);
    lp.x = (unsigned)l0 | ((unsigned)l1 << 16); lp.y = (unsigned)l2 | ((unsigned)l3 << 16);
    *(uint2*)&dst[idx * 4] = hp;
    *(uint2*)&dst[loOff + idx * 4] = lp;
}

// ---------------- f32 -> single bf16 plane ----------------
__global__ void convert_bf16_kernel(const float* __restrict__ src, unsigned short* __restrict__ dst,
                                    long long n4) {
    long long idx = (long long)blockIdx.x * 256 + threadIdx.x;
    if (idx >= n4) return;
    float4 v = ((const float4*)src)[idx];
    ushort4 o;
    o.x = bf16rne(v.x); o.y = bf16rne(v.y); o.z = bf16rne(v.z); o.w = bf16rne(v.w);
    *(ushort4*)&dst[idx * 4] = o;
}

// ------------- inp [z][512][768] f32 -> inp^T [z][768][512] bf16 -------------
__global__ void transpose_bf16_kernel(const float* __restrict__ inp, unsigned short* __restrict__ dst) {
    __shared__ float T[64][65];
    const int z = blockIdx.z;
    const int i0 = blockIdx.x * 64, d0 = blockIdx.y * 64;
    const float* src = inp + (long long)z * 393216;
    unsigned short* dz = dst + (long long)z * 393216;
    const int cl = threadIdx.x & 63, rl = threadIdx.x >> 6;
    #pragma unroll 4
    for (int e = 0; e < 16; ++e) {
        int il = e * 4 + rl;
        T[il][cl] = src[(long long)(i0 + il) * 768 + d0 + cl];
    }
    __syncthreads();
    #pragma unroll 4
    for (int e = 0; e < 16; ++e) {
        int dl = e * 4 + rl;
        dz[(long long)(d0 + dl) * 512 + i0 + cl] = bf16rne(T[cl][dl]);
    }
}

// ---------------- pad linearc_w [768,766] -> planes [768,768] ----------------
__global__ void pad_lw_kernel(const float* __restrict__ Lw, unsigned short* __restrict__ Lp) {
    int idx = blockIdx.x * 256 + threadIdx.x;  // 589824
    int n = idx / 768, k = idx - n * 768;
    float v = (k < 766) ? Lw[n * 766 + k] : 0.f;
    unsigned short h, l; cvt_split(v, h, l);
    Lp[idx] = h; Lp[589824 + idx] = l;
}

// ---------------- stacked QK weights -> planes [3][1024][1536] ----------------
__global__ void convert_qkw_kernel(const float* __restrict__ Qw, const float* __restrict__ Kw,
                                   unsigned short* __restrict__ dst) {
    long long idx = (long long)blockIdx.x * 256 + threadIdx.x;  // < 1179648
    if (idx >= 1179648) return;
    long long e = idx * 4;
    int h = (int)(e / 1572864);
    int rem = (int)(e - (long long)h * 1572864);
    int row = rem / 1536, k = rem - row * 1536;
    const float* src = (row < 512) ? (Qw + ((long long)(h * 512 + row) * 1536 + k))
                                   : (Kw + ((long long)(h * 512 + row - 512) * 1536 + k));
    float4 v = *(const float4*)src;
    unsigned short h0,h1,h2,h3,l0,l1,l2,l3;
    cvt_split(v.x,h0,l0); cvt_split(v.y,h1,l1); cvt_split(v.z,h2,l2); cvt_split(v.w,h3,l3);
    uint2 hp, lp;
    hp.x = (unsigned)h0 | ((unsigned)h1 << 16); hp.y = (unsigned)h2 | ((unsigned)h3 << 16);
    lp.x = (unsigned)l0 | ((unsigned)l1 << 16); lp.y = (unsigned)l2 | ((unsigned)l3 << 16);
    *(uint2*)&dst[e] = hp;
    *(uint2*)&dst[4718592 + e] = lp;
}

// ---------------- stacked QK bias [3][1024] ----------------
__global__ void qkb_kernel(const float* __restrict__ Qb, const float* __restrict__ Kb,
                           float* __restrict__ qkb) {
    int i = blockIdx.x * 256 + threadIdx.x;
    if (i >= 3072) return;
    int h = i >> 10, r = i & 1023;
    qkb[i] = (r < 512) ? Qb[h * 512 + r] : Kb[h * 512 + r - 512];
}

// ========== MFMA GEMM, 128x128 tile, 32x32x16, BK=16, 2-phase dbuf ==========
// A: always bf16 planes, async (lo at +aLo; onepass -> hi only).
// bmode: 3=NT planes async (lo at +bLo), 2=conv f32 window (bias by m).
// cmode: 0=f32, 1=planes (lo at +cLo). n>=Nreal -> 0.
template<int TAG>
__global__ __launch_bounds__(256, 4)
void gemm_mfma_kernel(const unsigned short* __restrict__ Au, const void* __restrict__ Bv,
                      void* __restrict__ Cv, const float* __restrict__ bias,
                      int M, int N, int K, int lda, int ldb, int ldc,
                      long long sA, long long sB, long long sC,
                      float divd, int relu, long long aLo,
                      int bmode, long long bLo,
                      int cmode, long long cLo,
                      int Nreal, int onepass)
{
    __shared__ __align__(16) unsigned short AhS[2][2][128][8];
    __shared__ __align__(16) unsigned short AlS[2][2][128][8];
    __shared__ __align__(16) unsigned short BhS[2][2][128][8];
    __shared__ __align__(16) unsigned short BlS[2][2][128][8];

    const int z = blockIdx.z;
    const int tid = threadIdx.x;
    const int m0 = blockIdx.y * 128, n0 = blockIdx.x * 128;
    const int lane = tid & 63, wave = tid >> 6;
    const int wm = (wave & 1) * 64, wn = (wave >> 1) * 64;
    const int lk = lane >> 5, lm = lane & 31;

    const unsigned short* A = Au + z * sA;
    const float* Bf = (const float*)Bv + z * sB;
    const unsigned short* Bu = (const unsigned short*)Bv + z * sB;
    float* Cf = (float*)Cv + z * sC;
    unsigned short* Cu = (unsigned short*)Cv + z * sC;

    f32x16 acc[2][2];
    #pragma unroll
    for (int i = 0; i < 2; ++i)
        #pragma unroll
        for (int j = 0; j < 2; ++j)
            #pragma unroll
            for (int r = 0; r < 16; ++r) acc[i][j][r] = 0.f;

    // bmode=2 staging indices: n = (tid&31) + 32*wave, khalf = (tid>>5)&1
    const int c_nlo = tid & 31;
    const int c_khalf = (tid >> 5) & 1;
    const int c_n = wave * 32 + c_nlo;          // 0..127

    auto stage = [&](int kk, int b) {
        // A (128 x 16, hi[+lo] planes), async: q = l*4+wave -> plane,kc,rg
        const int lmaxA = onepass ? 1 : 2;
        for (int l = 0; l < lmaxA; ++l) {
            const int q = l * 4 + wave;
            const int kc = (q & 3) >> 1, rg = q & 1;
            const unsigned short* g = A + (long long)(m0 + rg * 64 + lane) * lda + kk + kc * 8
                                        + ((q >> 2) ? aLo : 0);
            gl_lds16(g, (q >> 2) ? &AlS[b][kc][rg * 64][0] : &AhS[b][kc][rg * 64][0]);
        }
        if (bmode == 3) {
            const int lmaxB = onepass ? 1 : 2;
            for (int l = 0; l < lmaxB; ++l) {
                const int q = l * 4 + wave;
                const int kc = (q & 3) >> 1, rg = q & 1;
                const unsigned short* g = Bu + (long long)(n0 + rg * 64 + lane) * ldb + kk + kc * 8
                                            + ((q >> 2) ? bLo : 0);
                gl_lds16(g, (q >> 2) ? &BlS[b][kc][rg * 64][0] : &BhS[b][kc][rg * 64][0]);
            }
        } else {
            // conv window: thread covers (n=c_n, kgroup = khalf+2r), 4 consecutive k
            // -> one uint2 per plane (4-way bank aliasing vs old 16-32-way).
            #pragma unroll
            for (int r = 0; r < 2; ++r) {
                const int kgroup = c_khalf + 2 * r;   // 0..3
                const int k4 = kgroup * 4;
                float vv[4];
                #pragma unroll
                for (int e = 0; e < 4; ++e) {
                    const int kg = kk + k4 + e;
                    const int ii = kg / 3, k3 = kg - ii * 3;
                    // edge cols >=768 read into next row; they only feed C cols >=Nreal (zeroed)
                    vv[e] = Bf[(long long)ii * 768 + (n0 + c_n) + k3];
                }
                unsigned short h0,h1,h2,h3,l0,l1,l2,l3;
                cvt_split(vv[0],h0,l0); cvt_split(vv[1],h1,l1);
                cvt_split(vv[2],h2,l2); cvt_split(vv[3],h3,l3);
                uint2 hp, lp;
                hp.x = (unsigned)h0 | ((unsigned)h1 << 16);
                hp.y = (unsigned)h2 | ((unsigned)h3 << 16);
                lp.x = (unsigned)l0 | ((unsigned)l1 << 16);
                lp.y = (unsigned)l2 | ((unsigned)l3 << 16);
                const int kc = kgroup >> 1, kp = (kgroup & 1) * 4;
                *(uint2*)&BhS[b][kc][c_n][kp] = hp;
                *(uint2*)&BlS[b][kc][c_n][kp] = lp;
            }
        }
    };

    const int nt = K >> 4;
    stage(0, 0);
    __syncthreads();
    int cur = 0;
    for (int t = 0; t < nt; ++t) {
        if (t + 1 < nt) stage((t + 1) << 4, cur ^ 1);
        bf16x8 ah[2], bh[2];
        #pragma unroll
        for (int i = 0; i < 2; ++i) ah[i] = *(const bf16x8*)&AhS[cur][lk][wm + i * 32 + lm][0];
        #pragma unroll
        for (int j = 0; j < 2; ++j) bh[j] = *(const bf16x8*)&BhS[cur][lk][wn + j * 32 + lm][0];
        if (onepass) {
            #pragma unroll
            for (int i = 0; i < 2; ++i)
                #pragma unroll
                for (int j = 0; j < 2; ++j)
                    acc[i][j] = __builtin_amdgcn_mfma_f32_32x32x16_bf16(ah[i], bh[j], acc[i][j], 0, 0, 0);
        } else {
            bf16x8 al[2], bl[2];
            #pragma unroll
            for (int i = 0; i < 2; ++i) al[i] = *(const bf16x8*)&AlS[cur][lk][wm + i * 32 + lm][0];
            #pragma unroll
            for (int j = 0; j < 2; ++j) bl[j] = *(const bf16x8*)&BlS[cur][lk][wn + j * 32 + lm][0];
            #pragma unroll
            for (int i = 0; i < 2; ++i)
                #pragma unroll
                for (int j = 0; j < 2; ++j) {
                    acc[i][j] = __builtin_amdgcn_mfma_f32_32x32x16_bf16(ah[i], bh[j], acc[i][j], 0, 0, 0);
                    acc[i][j] = __builtin_amdgcn_mfma_f32_32x32x16_bf16(ah[i], bl[j], acc[i][j], 0, 0, 0);
                    acc[i][j] = __builtin_amdgcn_mfma_f32_32x32x16_bf16(al[i], bh[j], acc[i][j], 0, 0, 0);
                }
        }
        __syncthreads();
        cur ^= 1;
    }
    // ---- epilogue: C/D layout col=lane&31, row=(reg&3)+8*(reg>>2)+4*(lane>>5) ----
    #pragma unroll
    for (int i = 0; i < 2; ++i) {
        #pragma unroll
        for (int j = 0; j < 2; ++j) {
            #pragma unroll
            for (int reg = 0; reg < 16; ++reg) {
                const int m = m0 + wm + i * 32 + (reg & 3) + 8 * (reg >> 2) + 4 * lk;
                const int n = n0 + wn + j * 32 + lm;
                float v = acc[i][j][reg];
                if (divd != 1.f) v = v / divd;
                if (bias) v += bias[bmode == 2 ? m : n];
                if (relu) v = fmaxf(v, 0.f);
                if (n >= Nreal) v = 0.f;
                if (cmode == 1) {
                    unsigned short h, l; cvt_split(v, h, l);
                    Cu[(long long)m * ldc + n] = h;
                    Cu[cLo + (long long)m * ldc + n] = l;
                } else {
                    Cf[(long long)m * ldc + n] = v;
                }
            }
        }
    }
}

// ---------------- row sum (+1) for adj ----------------
__global__ void rowsum_kernel(const float* __restrict__ A, float* __restrict__ out, int ncols) {
    const float* row = A + (long long)blockIdx.x * ncols;
    float s = 0.f;
    for (int j = threadIdx.x; j < ncols; j += 256) s += row[j];
    __shared__ float red[256];
    red[threadIdx.x] = s;
    __syncthreads();
    for (int st = 128; st > 0; st >>= 1) {
        if (threadIdx.x < st) red[threadIdx.x] += red[threadIdx.x + st];
        __syncthreads();
    }
    if (threadIdx.x == 0) out[blockIdx.x] = red[0] + 1.0f;
}

// ------------- GCN layer-0 epilogue -------------
__global__ void gcn_epilogue_kernel(const float* __restrict__ axw, const float* __restrict__ xw,
                                    const float* __restrict__ bias, const float* __restrict__ denom,
                                    float* __restrict__ out)
{
    long long idx = (long long)blockIdx.x * 256 + threadIdx.x;  // 8192*768
    int m = (int)(idx / 768);
    int d = (int)(idx - (long long)m * 768);
    float bb = bias[d];
    float v = (axw[idx] + bb) / denom[m];
    out[idx] = fmaxf(v, 0.f) + xw[idx] + bb;
}

// ------------- inputs -> XCAT planes cols 0..767 -------------
__global__ void copy_concat_kernel(const float* __restrict__ inp, unsigned short* __restrict__ xcat)
{
    long long idx = (long long)blockIdx.x * 256 + threadIdx.x;  // 8192*768
    int m = (int)(idx / 768);
    int d = (int)(idx - (long long)m * 768);
    unsigned short h, l; cvt_split(inp[idx], h, l);
    xcat[(long long)m * 1536 + d] = h;
    xcat[12582912LL + (long long)m * 1536 + d] = l;
}

// ------------- row softmax over 384 stored cols (ld=384) -------------
__global__ void softmax_kernel(float* __restrict__ P)
{
    float* row = P + (long long)blockIdx.x * 384;
    const int t = threadIdx.x;  // 128
    float v0 = row[t], v1 = row[t + 128], v2 = row[t + 256];
    float m = fmaxf(v0, fmaxf(v1, v2));
    #pragma unroll
    for (int off = 32; off > 0; off >>= 1) m = fmaxf(m, __shfl_down(m, off));
    __shared__ float redm[2];
    if ((t & 63) == 0) redm[t >> 6] = m;
    __syncthreads();
    m = fmaxf(redm[0], redm[1]);
    float e0 = expf(v0 - m), e1 = expf(v1 - m), e2 = expf(v2 - m);
    float s = e0 + e1 + e2;
    #pragma unroll
    for (int off = 32; off > 0; off >>= 1) s += __shfl_down(s, off);
    __shared__ float reds[2];
    if ((t & 63) == 0) reds[t >> 6] = s;
    __syncthreads();
    s = reds[0] + reds[1];
    row[t] = e0 / s;
    row[t + 128] = e1 / s;
    row[t + 256] = e2 / s;
}

// ------------- sums stage 1 (f64 partials) -------------
__global__ void sums1_kernel(const float* __restrict__ P, double* __restrict__ sump)
{
    int blk = blockIdx.x;
    int bh = blk >> 4, ch = blk & 15;
    const float* p = P + (long long)bh * 196608 + ch * 12288;
    double s = 0.0;
    for (int i = threadIdx.x; i < 12288; i += 256) s += (double)p[i];
    __shared__ double red[256];
    red[threadIdx.x] = s;
    __syncthreads();
    for (int st = 128; st > 0; st >>= 1) {
        if (threadIdx.x < st) red[threadIdx.x] += red[threadIdx.x + st];
        __syncthreads();
    }
    if (threadIdx.x == 0) sump[blk] = red[0];
}

// ------------- sums stage 2 + head decision -------------
__global__ void decide2_kernel(const double* __restrict__ sump, int* __restrict__ maxidx)
{
    __shared__ double s48[48];
    int t = threadIdx.x;
    if (t < 48) {
        double s = 0.0;
        for (int i = 0; i < 16; ++i) s += sump[t * 16 + i];
        s48[t] = s;
    }
    __syncthreads();
    if (t == 0) {
        float s[16][3], prob[16][3];
        for (int b = 0; b < 16; ++b)
            for (int h = 0; h < 3; ++h) s[b][h] = (float)s48[b * 3 + h];
        for (int h = 0; h < 3; ++h) {
            float m = -1e30f;
            for (int b = 0; b < 16; ++b) m = fmaxf(m, s[b][h]);
            float e[16]; float Z = 0.f;
            for (int b = 0; b < 16; ++b) { e[b] = expf(s[b][h] - m); Z += e[b]; }
            for (int b = 0; b < 16; ++b) prob[b][h] = e[b] / Z;
        }
        for (int b = 0; b < 16; ++b) {
            int best = 0; float bv = prob[b][0];
            for (int h = 1; h < 3; ++h) if (prob[b][h] > bv) { bv = prob[b][h]; best = h; }
            maxidx[b] = best;
        }
    }
}

// ------------- top2 stage 1 -------------
__global__ void top2a_kernel(const float* __restrict__ P, const int* __restrict__ maxidx,
                             float2* __restrict__ t2p)
{
    int blk = blockIdx.x;
    int b = blk >> 5, ch = blk & 31;
    const float* p = P + ((long long)b * 3 + maxidx[b]) * 196608 + ch * 6144;
    float m1 = -1e30f, m2 = -1e30f;
    for (int i = threadIdx.x; i < 6144; i += 256) {
        float v = p[i];
        if (v > m1) { m2 = m1; m1 = v; }
        else if (v > m2) { m2 = v; }
    }
    __shared__ float r1[256], r2[256];
    r1[threadIdx.x] = m1; r2[threadIdx.x] = m2;
    __syncthreads();
    if (threadIdx.x == 0) {
        float M1 = -1e30f, M2 = -1e30f;
        for (int i = 0; i < 256; ++i) {
            float a = r1[i], c = r2[i];
            if (a > M1) { M2 = M1; M1 = a; } else if (a > M2) { M2 = a; }
            if (c > M1) { M2 = M1; M1 = c; } else if (c > M2) { M2 = c; }
        }
        t2p[blk] = make_float2(M1, M2);
    }
}

// ------------- top2 stage 2 -------------
__global__ void top2b_kernel(const float2* __restrict__ t2p, float* __restrict__ thr)
{
    int b = blockIdx.x;
    if (threadIdx.x != 0) return;
    float M1 = -1e30f, M2 = -1e30f;
    for (int i = 0; i < 32; ++i) {
        float2 v = t2p[b * 32 + i];
        if (v.x > M1) { M2 = M1; M1 = v.x; } else if (v.x > M2) { M2 = v.x; }
        if (v.y > M1) { M2 = M1; M1 = v.y; } else if (v.y > M2) { M2 = v.y; }
    }
    thr[b] = M2;
}

// ------------- init nnz state -------------
__global__ void init_nnz_kernel(int* __restrict__ cntb, int* __restrict__ nnzc,
                                float* __restrict__ den2)
{
    int idx = blockIdx.x * 256 + threadIdx.x;
    if (idx < 16) cntb[idx] = 0;
    if (idx < 8192) { nnzc[idx] = 0; den2[idx] = 1.f; }
}

// ------------- scan P for p>=thr (exact >= tie semantics) -------------
__global__ void scan_thr_kernel(const float* __restrict__ P, const int* __restrict__ maxidx,
                                const float* __restrict__ thr, int* __restrict__ cntb,
                                int* __restrict__ pos)
{
    int blk = blockIdx.x;            // 16*12
    int b = blk / 12, ch = blk % 12;
    const float* p = P + ((long long)b * 3 + maxidx[b]) * 196608;
    float t = thr[b];
    int base = ch * 16384;
    for (int l = 0; l < 64; ++l) {
        int idx = base + threadIdx.x + l * 256;
        if (p[idx] >= t) {
            int q = atomicAdd(&cntb[b], 1);
            if (q < 16) {
                int i = idx / 384, j = idx - i * 384;
                pos[b * 16 + q] = (i << 16) | j;
            }
        }
    }
}

// ------------- build nnz lists + den2 -------------
__global__ void build_nnz_kernel(const int* __restrict__ cntb, const int* __restrict__ pos,
                                 int* __restrict__ nnzc, int* __restrict__ jn,
                                 float* __restrict__ jv, float* __restrict__ den2)
{
    int b = threadIdx.x;
    if (b >= 16 || blockIdx.x != 0) return;
    int c = cntb[b]; if (c > 16) c = 16;
    for (int e = 0; e < c; ++e) {
        int pk = pos[b * 16 + e];
        int i = pk >> 16, j = pk & 0xFFFF;
        float val;
        if (i == j) val = 1.f;
        else {
            int rev = (j << 16) | i;
            int found = 0;
            for (int e2 = 0; e2 < c; ++e2) if (pos[b * 16 + e2] == rev) found = 1;
            val = 1.f + (float)found;
        }
        int r = b * 512 + i;
        int slot = nnzc[r];
        if (slot < 4) { jn[r * 4 + slot] = b * 512 + j; jv[r * 4 + slot] = val; }
        nnzc[r] = slot + 1;
        den2[r] += val;
    }
}

// ------------- GCN layer-1 fused sparse epilogue -> OUTL1 planes -------------
__global__ void gcn1_epilogue_kernel(const float* __restrict__ XW1, const float* __restrict__ b1,
                                     const float* __restrict__ den2, const int* __restrict__ cnt,
                                     const int* __restrict__ jn, const float* __restrict__ jv,
                                     unsigned short* __restrict__ outp)
{
    int m = blockIdx.x;
    int c = cnt[m]; if (c > 4) c = 4;
    float d2 = den2[m];
    int js[4]; float vs[4];
    for (int s = 0; s < c; ++s) { js[s] = jn[m * 4 + s]; vs[s] = jv[m * 4 + s]; }
    const float* xrow = XW1 + (long long)m * 768;
    #pragma unroll
    for (int l = 0; l < 3; ++l) {
        int d = threadIdx.x + l * 256;
        float ax = 0.f;
        for (int s = 0; s < c; ++s) ax += vs[s] * XW1[(long long)js[s] * 768 + d];
        float bb = b1[d];
        float v = fmaxf((ax + bb) / d2, 0.f) + xrow[d] + bb;
        unsigned short h, lo; cvt_split(v, h, lo);
        outp[(long long)m * 768 + d] = h;
        outp[6291456LL + (long long)m * 768 + d] = lo;
    }
}

}  // namespace

extern "C" void kernel_launch(void* const* d_in, const int* in_sizes, int n_in,
                              void* d_out, int out_size, void* d_ws, size_t ws_size,
                              hipStream_t stream) {
    const float* adj = (const float*)d_in[0];
    const float* inp = (const float*)d_in[1];
    const float* W0w = (const float*)d_in[3];
    const float* W0b = (const float*)d_in[4];
    const float* W1w = (const float*)d_in[5];
    const float* W1b = (const float*)d_in[6];
    const float* Cw  = (const float*)d_in[7];
    const float* Cbi = (const float*)d_in[8];
    const float* Lw  = (const float*)d_in[9];
    const float* Lb  = (const float*)d_in[10];
    const float* F1  = (const float*)d_in[11];
    const float* F2  = (const float*)d_in[12];
    const float* Qw  = (const float*)d_in[13];
    const float* Qb  = (const float*)d_in[14];
    const float* Kw  = (const float*)d_in[15];
    const float* Kbi = (const float*)d_in[16];
    float* out = (float*)d_out;

    if (ws_size < (size_t)TOTAL_FLOATS * sizeof(float)) {
        sentinel_kernel<<<dim3(1), dim3(64), 0, stream>>>(out);
        return;
    }

    float* W = (float*)d_ws;
    float*   DEN   = W + O_DEN;
    float*   DEN2  = W + O_DEN2;
    double*  SUMP  = (double*)(W + O_SUMP);
    float*   THR   = W + O_THR;
    int*     MIDX  = (int*)(W + O_MIDX);
    int*     CNT   = (int*)(W + O_CNT);
    int*     POS   = (int*)(W + O_POS);
    float2*  T2P   = (float2*)(W + O_T2P);
    int*     NNZC  = (int*)(W + O_NNZC);
    int*     NNZJ  = (int*)(W + O_NNZJ);
    float*   NNZV  = W + O_NNZV;
    float*   QKB   = W + O_QKB;

    unsigned short* INPP  = (unsigned short*)(W + O_X);
    float*          OUT0  = W + O_X;
    unsigned short* XCATp = (unsigned short*)(W + O_X);
    unsigned short* F1P   = (unsigned short*)(W + O_X);
    unsigned short* F2P   = (unsigned short*)(W + O_X + 589824);

    unsigned short* AXp    = (unsigned short*)(W + OZ);
    float*          AXW0f  = W + OZ + 6291456;
    float*          XW0f   = W + O_X + 6291456;           // X-region second half
    unsigned short* W0P    = (unsigned short*)(W + OZ + 12582912);
    unsigned short* ADJB   = (unsigned short*)(W + OZ + 13172736);  // 2.1M floats
    unsigned short* CONVEp = (unsigned short*)(W + OZ);
    unsigned short* CwP    = (unsigned short*)(W + OZ + 6291456);
    unsigned short* LWPp   = (unsigned short*)(W + OZ + 7077888);
    unsigned short* QKp    = (unsigned short*)(W + OZ);
    float*          P      = W + OZ + 8388608;
    float*          XW1f   = W + OZ;
    unsigned short* OUTL1p = (unsigned short*)(W + OZ + 6291456);
    unsigned short* H1p    = (unsigned short*)(W + OZ);

    unsigned short* INPTB  = (unsigned short*)out;         // ph1 only
    unsigned short* QKwP   = (unsigned short*)out;
    unsigned short* W1P    = (unsigned short*)(out + 4718592);

    const float divs = sqrtf(512.0f);
    const int BIGN = 1 << 30;

    // ---- phase 1: GCN layer 0 ----
    convert_planes_kernel<<<dim3(6144), dim3(256), 0, stream>>>(inp, INPP, 6291456, 1572864);
    convert_planes_kernel<<<dim3(576), dim3(256), 0, stream>>>(W0w, W0P, 589824, 147456);
    convert_bf16_kernel<<<dim3(4096), dim3(256), 0, stream>>>(adj, ADJB, 1048576);
    transpose_bf16_kernel<<<dim3(8, 12, 16), dim3(256), 0, stream>>>(inp, INPTB);
    qkb_kernel<<<dim3(12), dim3(256), 0, stream>>>(Qb, Kbi, QKB);
    rowsum_kernel<<<dim3(8192), dim3(256), 0, stream>>>(adj, DEN, 512);
    // AX = adj @ inputs -> planes (1-pass bf16: error /denom(~257) ~3e-4)
    gemm_mfma_kernel<0><<<dim3(6, 4, 16), dim3(256), 0, stream>>>(
        ADJB, INPTB, AXp, nullptr, 512, 768, 512, 512, 512, 768,
        262144LL, 393216LL, 393216LL, 1.f, 0, 0, 3, 0, 1, 6291456LL, BIGN, 1);
    // XW0 = inp @ W0^T (z=0) and AXW0 = AX @ W0^T (z=1), merged via z-strides
    gemm_mfma_kernel<1><<<dim3(6, 64, 2), dim3(256), 0, stream>>>(
        INPP, W0P, XW0f, nullptr, 8192, 768, 768, 768, 768, 768,
        25165824LL, 0, 12582912LL, 1.f, 0, 6291456LL, 3, 589824LL, 0, 0, BIGN, 0);
    gcn_epilogue_kernel<<<dim3(24576), dim3(256), 0, stream>>>(AXW0f, XW0f, W0b, DEN, OUT0);

    // ---- weight conversions (d_out free after AX; Z tails free) ----
    convert_planes_kernel<<<dim3(768), dim3(256), 0, stream>>>(Cw, CwP, 786432, 196608);
    pad_lw_kernel<<<dim3(2304), dim3(256), 0, stream>>>(Lw, LWPp);
    convert_qkw_kernel<<<dim3(4608), dim3(256), 0, stream>>>(Qw, Kw, QKwP);
    convert_planes_kernel<<<dim3(1152), dim3(256), 0, stream>>>(W1w, W1P, 1179648, 294912);

    // ---- phase 2: conv + linearc -> xcat planes ----
    gemm_mfma_kernel<2><<<dim3(6, 4, 16), dim3(256), 0, stream>>>(
        CwP, OUT0, CONVEp, Cbi, 512, 768, 1536, 1536, 0, 768,
        0, 393216LL, 393216LL, 1.f, 1, 786432LL, 2, 0, 1, 6291456LL, 766, 0);
    gemm_mfma_kernel<3><<<dim3(6, 64, 1), dim3(256), 0, stream>>>(
        CONVEp, LWPp, (void*)(XCATp + 768), Lb, 8192, 768, 768, 768, 768, 1536,
        0, 0, 0, 1.f, 0, 6291456LL, 3, 589824LL, 1, 12582912LL, BIGN, 0);
    copy_concat_kernel<<<dim3(24576), dim3(256), 0, stream>>>(inp, XCATp);

    // ---- phase 3: merged QK projection + scores per head ----
    for (int h = 0; h < 3; ++h) {
        gemm_mfma_kernel<4><<<dim3(8, 64, 1), dim3(256), 0, stream>>>(
            XCATp, QKwP + (long long)h * 1572864, QKp, QKB + h * 1024,
            8192, 1024, 1536, 1536, 1536, 1024,
            0, 0, 0, 1.f, 0, 12582912LL, 3, 4718592LL, 1, 8388608LL, BIGN, 0);
        gemm_mfma_kernel<5><<<dim3(3, 4, 16), dim3(256), 0, stream>>>(
            QKp, QKp + 512, P + (long long)h * 196608, nullptr,
            512, 384, 512, 1024, 1024, 384,
            524288LL, 524288LL, 589824LL, divs, 0, 8388608LL, 3, 8388608LL, 0, 0, BIGN, 0);
    }

    // ---- softmax + decisions ----
    softmax_kernel<<<dim3(24576), dim3(128), 0, stream>>>(P);
    sums1_kernel<<<dim3(768), dim3(256), 0, stream>>>(P, SUMP);
    decide2_kernel<<<dim3(1), dim3(64), 0, stream>>>(SUMP, MIDX);
    top2a_kernel<<<dim3(512), dim3(256), 0, stream>>>(P, MIDX, T2P);
    top2b_kernel<<<dim3(16), dim3(64), 0, stream>>>(T2P, THR);
    init_nnz_kernel<<<dim3(32), dim3(256), 0, stream>>>(CNT, NNZC, DEN2);
    scan_thr_kernel<<<dim3(192), dim3(256), 0, stream>>>(P, MIDX, THR, CNT, POS);
    build_nnz_kernel<<<dim3(1), dim3(64), 0, stream>>>(CNT, POS, NNZC, NNZJ, NNZV, DEN2);

    // ---- phase 5: GCN layer 1 (sparse adj2) + fc ----
    gemm_mfma_kernel<6><<<dim3(6, 64, 1), dim3(256), 0, stream>>>(
        XCATp, W1P, XW1f, nullptr, 8192, 768, 1536, 1536, 1536, 768,
        0, 0, 0, 1.f, 0, 12582912LL, 3, 1179648LL, 0, 0, BIGN, 0);
    convert_planes_kernel<<<dim3(576), dim3(256), 0, stream>>>(F1, F1P, 589824, 147456);
    convert_planes_kernel<<<dim3(576), dim3(256), 0, stream>>>(F2, F2P, 589824, 147456);
    gcn1_epilogue_kernel<<<dim3(8192), dim3(256), 0, stream>>>(XW1f, W1b, DEN2, NNZC, NNZJ, NNZV, OUTL1p);
    gemm_mfma_kernel<7><<<dim3(6, 64, 1), dim3(256), 0, stream>>>(
        OUTL1p, F1P, H1p, nullptr, 8192, 768, 768, 768, 768, 768,
        0, 0, 0, 1.f, 1, 6291456LL, 3, 589824LL, 1, 6291456LL, BIGN, 0);
    gemm_mfma_kernel<8><<<dim3(6, 64, 1), dim3(256), 0, stream>>>(
        H1p, F2P, out, nullptr, 8192, 768, 768, 768, 768, 768,
        0, 0, 0, 1.f, 0, 6291456LL, 3, 589824LL, 0, 0, BIGN, 0);
}

// Round 4
// 1571.410 us; speedup vs baseline: 5.7515x; 5.7515x over previous
//
#include <hip/hip_runtime.h>
#include <math.h>

// B=16, N=512, D=768, Dh=1536, HEADS=3, keys>=384 masked.
// GEMM core: 128x128 tile, 32x32x16 MFMA, BK=16, DOUBLE-BUFFERED LDS,
// 2-phase pipeline: stage(t+1) issued before compute(t), one barrier/step.
// bf16x2 hi/lo split (3-pass) for precision-critical GEMMs; AX (adj@inp) runs
// 1-pass bf16 (error /denom~257 -> ~3e-4, under threshold).
// BMODE/CMODE/ONEPASS are TEMPLATE params (round-3 lesson: runtime modes +
// __launch_bounds__(256,4) on the unified 512-reg file capped regs at 128,
// spilling acc -> 3.2GB scratch writes/dispatch). launch_bounds(256,2).
//
// Arena (float units), 30539776 (~122.2 MB):
//  S [0,131072): scalars/lists (+QKB bias at 93184)
//  X [131072,+12582912): INPP planes (first half) + XW0f (second half) ->
//    OUT0 f32 -> XCATp planes -> F1P/F2P
//  Z = 12713984 (+17825792):
//   ph1: AXp[0,6.29M) AXW0f[6.29,12.58M) W0P[12.58,13.17M) ADJB[13.17,15.27M)
//   ph2: CONVEp[0,6.29M) CwP[6.29,7.08M) LWPp[7.08,7.67M)
//   ph3: QKp planes[0,8.39M) P f32[8.39,17.83M)
//   ph5: XW1f[0,6.29M) OUTL1p[6.29,12.58M) H1p[0,6.29M after XW1f dead)
//  d_out: ph1 INPTB bf16[0,3.15M); then QKwP[0,4.72M) W1P[4.72,5.9M); final out.

namespace {

constexpr long long O_DEN  = 0;
constexpr long long O_DEN2 = 8192;
constexpr long long O_SUMP = 16384;
constexpr long long O_THR  = 17920;
constexpr long long O_MIDX = 17936;
constexpr long long O_CNT  = 17952;
constexpr long long O_POS  = 17968;
constexpr long long O_T2P  = 18224;
constexpr long long O_NNZC = 19456;
constexpr long long O_NNZJ = 27648;
constexpr long long O_NNZV = 60416;
constexpr long long O_QKB  = 93184;   // 3072 floats

constexpr long long O_X    = 131072;
constexpr long long OZ     = 131072 + 12582912;          // 12713984
constexpr long long TOTAL_FLOATS = OZ + 17825792;        // 30539776

typedef short bf16x8 __attribute__((ext_vector_type(8)));
typedef float f32x4 __attribute__((ext_vector_type(4)));
typedef float f32x16 __attribute__((ext_vector_type(16)));

__global__ void sentinel_kernel(float* out) {
    if (threadIdx.x == 0 && blockIdx.x == 0) out[0] = 1.0e6f;
}

__device__ __forceinline__ unsigned short bf16rne(float f) {
    union { float x; unsigned u; } a; a.x = f;
    return (unsigned short)((a.u + 0x7FFFu + ((a.u >> 16) & 1u)) >> 16);
}

// RNE f32 -> bf16 hi + bf16(residual)
__device__ __forceinline__ void cvt_split(float f, unsigned short& h, unsigned short& l) {
    union { float x; unsigned u; } a; a.x = f;
    unsigned hb = (a.u + 0x7FFFu + ((a.u >> 16) & 1u)) & 0xFFFF0000u;
    h = (unsigned short)(hb >> 16);
    union { unsigned u; float x; } b; b.u = hb;
    float r = f - b.x;
    union { float x; unsigned u; } c; c.x = r;
    l = (unsigned short)((c.u + 0x7FFFu + ((c.u >> 16) & 1u)) >> 16);
}

// async 16B global->LDS (lds dest: wave-uniform base + lane*16)
__device__ __forceinline__ void gl_lds16(const unsigned short* g, unsigned short* l) {
    __builtin_amdgcn_global_load_lds(
        (const __attribute__((address_space(1))) unsigned int*)g,
        (__attribute__((address_space(3))) unsigned int*)l,
        16, 0, 0);
}

// ---------------- f32 -> planes converter ----------------
__global__ void convert_planes_kernel(const float* __restrict__ src, unsigned short* __restrict__ dst,
                                      long long loOff, long long n4) {
    long long idx = (long long)blockIdx.x * 256 + threadIdx.x;
    if (idx >= n4) return;
    float4 v = ((const float4*)src)[idx];
    unsigned short h0,h1,h2,h3,l0,l1,l2,l3;
    cvt_split(v.x,h0,l0); cvt_split(v.y,h1,l1); cvt_split(v.z,h2,l2); cvt_split(v.w,h3,l3);
    uint2 hp, lp;
    hp.x = (unsigned)h0 | ((unsigned)h1 << 16); hp.y = (unsigned)h2 | ((unsigned)h3 << 16);
    lp.x = (unsigned)l0 | ((unsigned)l1 << 16); lp.y = (unsigned)l2 | ((unsigned)l3 << 16);
    *(uint2*)&dst[idx * 4] = hp;
    *(uint2*)&dst[loOff + idx * 4] = lp;
}

// ---------------- f32 -> single bf16 plane ----------------
__global__ void convert_bf16_kernel(const float* __restrict__ src, unsigned short* __restrict__ dst,
                                    long long n4) {
    long long idx = (long long)blockIdx.x * 256 + threadIdx.x;
    if (idx >= n4) return;
    float4 v = ((const float4*)src)[idx];
    ushort4 o;
    o.x = bf16rne(v.x); o.y = bf16rne(v.y); o.z = bf16rne(v.z); o.w = bf16rne(v.w);
    *(ushort4*)&dst[idx * 4] = o;
}

// ------------- inp [z][512][768] f32 -> inp^T [z][768][512] bf16 -------------
__global__ void transpose_bf16_kernel(const float* __restrict__ inp, unsigned short* __restrict__ dst) {
    __shared__ float T[64][65];
    const int z = blockIdx.z;
    const int i0 = blockIdx.x * 64, d0 = blockIdx.y * 64;
    const float* src = inp + (long long)z * 393216;
    unsigned short* dz = dst + (long long)z * 393216;
    const int cl = threadIdx.x & 63, rl = threadIdx.x >> 6;
    #pragma unroll 4
    for (int e = 0; e < 16; ++e) {
        int il = e * 4 + rl;
        T[il][cl] = src[(long long)(i0 + il) * 768 + d0 + cl];
    }
    __syncthreads();
    #pragma unroll 4
    for (int e = 0; e < 16; ++e) {
        int dl = e * 4 + rl;
        dz[(long long)(d0 + dl) * 512 + i0 + cl] = bf16rne(T[cl][dl]);
    }
}

// ---------------- pad linearc_w [768,766] -> planes [768,768] ----------------
__global__ void pad_lw_kernel(const float* __restrict__ Lw, unsigned short* __restrict__ Lp) {
    int idx = blockIdx.x * 256 + threadIdx.x;  // 589824
    int n = idx / 768, k = idx - n * 768;
    float v = (k < 766) ? Lw[n * 766 + k] : 0.f;
    unsigned short h, l; cvt_split(v, h, l);
    Lp[idx] = h; Lp[589824 + idx] = l;
}

// ---------------- stacked QK weights -> planes [3][1024][1536] ----------------
__global__ void convert_qkw_kernel(const float* __restrict__ Qw, const float* __restrict__ Kw,
                                   unsigned short* __restrict__ dst) {
    long long idx = (long long)blockIdx.x * 256 + threadIdx.x;  // < 1179648
    if (idx >= 1179648) return;
    long long e = idx * 4;
    int h = (int)(e / 1572864);
    int rem = (int)(e - (long long)h * 1572864);
    int row = rem / 1536, k = rem - row * 1536;
    const float* src = (row < 512) ? (Qw + ((long long)(h * 512 + row) * 1536 + k))
                                   : (Kw + ((long long)(h * 512 + row - 512) * 1536 + k));
    float4 v = *(const float4*)src;
    unsigned short h0,h1,h2,h3,l0,l1,l2,l3;
    cvt_split(v.x,h0,l0); cvt_split(v.y,h1,l1); cvt_split(v.z,h2,l2); cvt_split(v.w,h3,l3);
    uint2 hp, lp;
    hp.x = (unsigned)h0 | ((unsigned)h1 << 16); hp.y = (unsigned)h2 | ((unsigned)h3 << 16);
    lp.x = (unsigned)l0 | ((unsigned)l1 << 16); lp.y = (unsigned)l2 | ((unsigned)l3 << 16);
    *(uint2*)&dst[e] = hp;
    *(uint2*)&dst[4718592 + e] = lp;
}

// ---------------- stacked QK bias [3][1024] ----------------
__global__ void qkb_kernel(const float* __restrict__ Qb, const float* __restrict__ Kb,
                           float* __restrict__ qkb) {
    int i = blockIdx.x * 256 + threadIdx.x;
    if (i >= 3072) return;
    int h = i >> 10, r = i & 1023;
    qkb[i] = (r < 512) ? Qb[h * 512 + r] : Kb[h * 512 + r - 512];
}

// ========== MFMA GEMM, 128x128 tile, 32x32x16, BK=16, 2-phase dbuf ==========
// A: always bf16 planes, async (lo at +aLo; ONEPASS -> hi only).
// BMODE: 3=NT planes async (lo at +bLo), 2=conv f32 window (bias by m).
// CMODE: 0=f32, 1=planes (lo at +cLo). n>=Nreal -> 0.
template<int TAG, int BMODE, int CMODE, int ONEPASS>
__global__ __launch_bounds__(256, 2)
void gemm_mfma_kernel(const unsigned short* __restrict__ Au, const void* __restrict__ Bv,
                      void* __restrict__ Cv, const float* __restrict__ bias,
                      int M, int N, int K, int lda, int ldb, int ldc,
                      long long sA, long long sB, long long sC,
                      float divd, int relu, long long aLo,
                      long long bLo, long long cLo, int Nreal)
{
    __shared__ __align__(16) unsigned short AhS[2][2][128][8];
    __shared__ __align__(16) unsigned short BhS[2][2][128][8];
    __shared__ __align__(16) unsigned short AlS[ONEPASS ? 1 : 2][2][128][8];
    __shared__ __align__(16) unsigned short BlS[ONEPASS ? 1 : 2][2][128][8];

    const int z = blockIdx.z;
    const int tid = threadIdx.x;
    const int m0 = blockIdx.y * 128, n0 = blockIdx.x * 128;
    const int lane = tid & 63, wave = tid >> 6;
    const int wm = (wave & 1) * 64, wn = (wave >> 1) * 64;
    const int lk = lane >> 5, lm = lane & 31;

    const unsigned short* A = Au + z * sA;
    const float* Bf = (const float*)Bv + z * sB;
    const unsigned short* Bu = (const unsigned short*)Bv + z * sB;
    float* Cf = (float*)Cv + z * sC;
    unsigned short* Cu = (unsigned short*)Cv + z * sC;

    f32x16 acc[2][2];
    #pragma unroll
    for (int i = 0; i < 2; ++i)
        #pragma unroll
        for (int j = 0; j < 2; ++j)
            #pragma unroll
            for (int r = 0; r < 16; ++r) acc[i][j][r] = 0.f;

    // BMODE=2 staging indices
    const int c_nlo = tid & 31;
    const int c_khalf = (tid >> 5) & 1;
    const int c_n = wave * 32 + c_nlo;          // 0..127

    auto stage = [&](int kk, int b) {
        // A (128 x 16, hi[+lo] planes), async: q = l*4+wave -> plane,kc,rg
        #pragma unroll
        for (int l = 0; l < (ONEPASS ? 1 : 2); ++l) {
            const int q = l * 4 + wave;
            const int kc = (q & 3) >> 1, rg = q & 1;
            const unsigned short* g = A + (long long)(m0 + rg * 64 + lane) * lda + kk + kc * 8
                                        + ((q >> 2) ? aLo : 0);
            gl_lds16(g, (q >> 2) ? &AlS[b][kc][rg * 64][0] : &AhS[b][kc][rg * 64][0]);
        }
        if constexpr (BMODE == 3) {
            #pragma unroll
            for (int l = 0; l < (ONEPASS ? 1 : 2); ++l) {
                const int q = l * 4 + wave;
                const int kc = (q & 3) >> 1, rg = q & 1;
                const unsigned short* g = Bu + (long long)(n0 + rg * 64 + lane) * ldb + kk + kc * 8
                                            + ((q >> 2) ? bLo : 0);
                gl_lds16(g, (q >> 2) ? &BlS[b][kc][rg * 64][0] : &BhS[b][kc][rg * 64][0]);
            }
        } else {
            // conv window: thread covers (n=c_n, kgroup = khalf+2r), 4 consecutive k
            // -> one uint2 per plane (~4-way bank aliasing).
            #pragma unroll
            for (int r = 0; r < 2; ++r) {
                const int kgroup = c_khalf + 2 * r;   // 0..3
                const int k4 = kgroup * 4;
                float vv[4];
                #pragma unroll
                for (int e = 0; e < 4; ++e) {
                    const int kg = kk + k4 + e;
                    const int ii = kg / 3, k3 = kg - ii * 3;
                    // edge cols >=768 read into next row; they only feed C cols >=Nreal (zeroed)
                    vv[e] = Bf[(long long)ii * 768 + (n0 + c_n) + k3];
                }
                unsigned short h0,h1,h2,h3,l0,l1,l2,l3;
                cvt_split(vv[0],h0,l0); cvt_split(vv[1],h1,l1);
                cvt_split(vv[2],h2,l2); cvt_split(vv[3],h3,l3);
                uint2 hp, lp;
                hp.x = (unsigned)h0 | ((unsigned)h1 << 16);
                hp.y = (unsigned)h2 | ((unsigned)h3 << 16);
                lp.x = (unsigned)l0 | ((unsigned)l1 << 16);
                lp.y = (unsigned)l2 | ((unsigned)l3 << 16);
                const int kc = kgroup >> 1, kp = (kgroup & 1) * 4;
                *(uint2*)&BhS[b][kc][c_n][kp] = hp;
                *(uint2*)&BlS[b][kc][c_n][kp] = lp;
            }
        }
    };

    const int nt = K >> 4;
    stage(0, 0);
    __syncthreads();
    int cur = 0;
    for (int t = 0; t < nt; ++t) {
        if (t + 1 < nt) stage((t + 1) << 4, cur ^ 1);
        bf16x8 ah[2], bh[2];
        #pragma unroll
        for (int i = 0; i < 2; ++i) ah[i] = *(const bf16x8*)&AhS[cur][lk][wm + i * 32 + lm][0];
        #pragma unroll
        for (int j = 0; j < 2; ++j) bh[j] = *(const bf16x8*)&BhS[cur][lk][wn + j * 32 + lm][0];
        if constexpr (ONEPASS) {
            #pragma unroll
            for (int i = 0; i < 2; ++i)
                #pragma unroll
                for (int j = 0; j < 2; ++j)
                    acc[i][j] = __builtin_amdgcn_mfma_f32_32x32x16_bf16(ah[i], bh[j], acc[i][j], 0, 0, 0);
        } else {
            bf16x8 al[2], bl[2];
            #pragma unroll
            for (int i = 0; i < 2; ++i) al[i] = *(const bf16x8*)&AlS[cur][lk][wm + i * 32 + lm][0];
            #pragma unroll
            for (int j = 0; j < 2; ++j) bl[j] = *(const bf16x8*)&BlS[cur][lk][wn + j * 32 + lm][0];
            #pragma unroll
            for (int i = 0; i < 2; ++i)
                #pragma unroll
                for (int j = 0; j < 2; ++j) {
                    acc[i][j] = __builtin_amdgcn_mfma_f32_32x32x16_bf16(ah[i], bh[j], acc[i][j], 0, 0, 0);
                    acc[i][j] = __builtin_amdgcn_mfma_f32_32x32x16_bf16(ah[i], bl[j], acc[i][j], 0, 0, 0);
                    acc[i][j] = __builtin_amdgcn_mfma_f32_32x32x16_bf16(al[i], bh[j], acc[i][j], 0, 0, 0);
                }
        }
        __syncthreads();
        cur ^= 1;
    }
    // ---- epilogue: C/D layout col=lane&31, row=(reg&3)+8*(reg>>2)+4*(lane>>5) ----
    #pragma unroll
    for (int i = 0; i < 2; ++i) {
        #pragma unroll
        for (int j = 0; j < 2; ++j) {
            #pragma unroll
            for (int reg = 0; reg < 16; ++reg) {
                const int m = m0 + wm + i * 32 + (reg & 3) + 8 * (reg >> 2) + 4 * lk;
                const int n = n0 + wn + j * 32 + lm;
                float v = acc[i][j][reg];
                if (divd != 1.f) v = v / divd;
                if (bias) v += bias[BMODE == 2 ? m : n];
                if (relu) v = fmaxf(v, 0.f);
                if (n >= Nreal) v = 0.f;
                if constexpr (CMODE == 1) {
                    unsigned short h, l; cvt_split(v, h, l);
                    Cu[(long long)m * ldc + n] = h;
                    Cu[cLo + (long long)m * ldc + n] = l;
                } else {
                    Cf[(long long)m * ldc + n] = v;
                }
            }
        }
    }
}

// ---------------- row sum (+1) for adj ----------------
__global__ void rowsum_kernel(const float* __restrict__ A, float* __restrict__ out, int ncols) {
    const float* row = A + (long long)blockIdx.x * ncols;
    float s = 0.f;
    for (int j = threadIdx.x; j < ncols; j += 256) s += row[j];
    __shared__ float red[256];
    red[threadIdx.x] = s;
    __syncthreads();
    for (int st = 128; st > 0; st >>= 1) {
        if (threadIdx.x < st) red[threadIdx.x] += red[threadIdx.x + st];
        __syncthreads();
    }
    if (threadIdx.x == 0) out[blockIdx.x] = red[0] + 1.0f;
}

// ------------- GCN layer-0 epilogue -------------
__global__ void gcn_epilogue_kernel(const float* __restrict__ axw, const float* __restrict__ xw,
                                    const float* __restrict__ bias, const float* __restrict__ denom,
                                    float* __restrict__ out)
{
    long long idx = (long long)blockIdx.x * 256 + threadIdx.x;  // 8192*768
    int m = (int)(idx / 768);
    int d = (int)(idx - (long long)m * 768);
    float bb = bias[d];
    float v = (axw[idx] + bb) / denom[m];
    out[idx] = fmaxf(v, 0.f) + xw[idx] + bb;
}

// ------------- inputs -> XCAT planes cols 0..767 -------------
__global__ void copy_concat_kernel(const float* __restrict__ inp, unsigned short* __restrict__ xcat)
{
    long long idx = (long long)blockIdx.x * 256 + threadIdx.x;  // 8192*768
    int m = (int)(idx / 768);
    int d = (int)(idx - (long long)m * 768);
    unsigned short h, l; cvt_split(inp[idx], h, l);
    xcat[(long long)m * 1536 + d] = h;
    xcat[12582912LL + (long long)m * 1536 + d] = l;
}

// ------------- row softmax over 384 stored cols (ld=384) -------------
__global__ void softmax_kernel(float* __restrict__ P)
{
    float* row = P + (long long)blockIdx.x * 384;
    const int t = threadIdx.x;  // 128
    float v0 = row[t], v1 = row[t + 128], v2 = row[t + 256];
    float m = fmaxf(v0, fmaxf(v1, v2));
    #pragma unroll
    for (int off = 32; off > 0; off >>= 1) m = fmaxf(m, __shfl_down(m, off));
    __shared__ float redm[2];
    if ((t & 63) == 0) redm[t >> 6] = m;
    __syncthreads();
    m = fmaxf(redm[0], redm[1]);
    float e0 = expf(v0 - m), e1 = expf(v1 - m), e2 = expf(v2 - m);
    float s = e0 + e1 + e2;
    #pragma unroll
    for (int off = 32; off > 0; off >>= 1) s += __shfl_down(s, off);
    __shared__ float reds[2];
    if ((t & 63) == 0) reds[t >> 6] = s;
    __syncthreads();
    s = reds[0] + reds[1];
    row[t] = e0 / s;
    row[t + 128] = e1 / s;
    row[t + 256] = e2 / s;
}

// ------------- sums stage 1 (f64 partials) -------------
__global__ void sums1_kernel(const float* __restrict__ P, double* __restrict__ sump)
{
    int blk = blockIdx.x;
    int bh = blk >> 4, ch = blk & 15;
    const float* p = P + (long long)bh * 196608 + ch * 12288;
    double s = 0.0;
    for (int i = threadIdx.x; i < 12288; i += 256) s += (double)p[i];
    __shared__ double red[256];
    red[threadIdx.x] = s;
    __syncthreads();
    for (int st = 128; st > 0; st >>= 1) {
        if (threadIdx.x < st) red[threadIdx.x] += red[threadIdx.x + st];
        __syncthreads();
    }
    if (threadIdx.x == 0) sump[blk] = red[0];
}

// ------------- sums stage 2 + head decision -------------
__global__ void decide2_kernel(const double* __restrict__ sump, int* __restrict__ maxidx)
{
    __shared__ double s48[48];
    int t = threadIdx.x;
    if (t < 48) {
        double s = 0.0;
        for (int i = 0; i < 16; ++i) s += sump[t * 16 + i];
        s48[t] = s;
    }
    __syncthreads();
    if (t == 0) {
        float s[16][3], prob[16][3];
        for (int b = 0; b < 16; ++b)
            for (int h = 0; h < 3; ++h) s[b][h] = (float)s48[b * 3 + h];
        for (int h = 0; h < 3; ++h) {
            float m = -1e30f;
            for (int b = 0; b < 16; ++b) m = fmaxf(m, s[b][h]);
            float e[16]; float Z = 0.f;
            for (int b = 0; b < 16; ++b) { e[b] = expf(s[b][h] - m); Z += e[b]; }
            for (int b = 0; b < 16; ++b) prob[b][h] = e[b] / Z;
        }
        for (int b = 0; b < 16; ++b) {
            int best = 0; float bv = prob[b][0];
            for (int h = 1; h < 3; ++h) if (prob[b][h] > bv) { bv = prob[b][h]; best = h; }
            maxidx[b] = best;
        }
    }
}

// ------------- top2 stage 1 -------------
__global__ void top2a_kernel(const float* __restrict__ P, const int* __restrict__ maxidx,
                             float2* __restrict__ t2p)
{
    int blk = blockIdx.x;
    int b = blk >> 5, ch = blk & 31;
    const float* p = P + ((long long)b * 3 + maxidx[b]) * 196608 + ch * 6144;
    float m1 = -1e30f, m2 = -1e30f;
    for (int i = threadIdx.x; i < 6144; i += 256) {
        float v = p[i];
        if (v > m1) { m2 = m1; m1 = v; }
        else if (v > m2) { m2 = v; }
    }
    __shared__ float r1[256], r2[256];
    r1[threadIdx.x] = m1; r2[threadIdx.x] = m2;
    __syncthreads();
    if (threadIdx.x == 0) {
        float M1 = -1e30f, M2 = -1e30f;
        for (int i = 0; i < 256; ++i) {
            float a = r1[i], c = r2[i];
            if (a > M1) { M2 = M1; M1 = a; } else if (a > M2) { M2 = a; }
            if (c > M1) { M2 = M1; M1 = c; } else if (c > M2) { M2 = c; }
        }
        t2p[blk] = make_float2(M1, M2);
    }
}

// ------------- top2 stage 2 -------------
__global__ void top2b_kernel(const float2* __restrict__ t2p, float* __restrict__ thr)
{
    int b = blockIdx.x;
    if (threadIdx.x != 0) return;
    float M1 = -1e30f, M2 = -1e30f;
    for (int i = 0; i < 32; ++i) {
        float2 v = t2p[b * 32 + i];
        if (v.x > M1) { M2 = M1; M1 = v.x; } else if (v.x > M2) { M2 = v.x; }
        if (v.y > M1) { M2 = M1; M1 = v.y; } else if (v.y > M2) { M2 = v.y; }
    }
    thr[b] = M2;
}

// ------------- init nnz state -------------
__global__ void init_nnz_kernel(int* __restrict__ cntb, int* __restrict__ nnzc,
                                float* __restrict__ den2)
{
    int idx = blockIdx.x * 256 + threadIdx.x;
    if (idx < 16) cntb[idx] = 0;
    if (idx < 8192) { nnzc[idx] = 0; den2[idx] = 1.f; }
}

// ------------- scan P for p>=thr (exact >= tie semantics) -------------
__global__ void scan_thr_kernel(const float* __restrict__ P, const int* __restrict__ maxidx,
                                const float* __restrict__ thr, int* __restrict__ cntb,
                                int* __restrict__ pos)
{
    int blk = blockIdx.x;            // 16*12
    int b = blk / 12, ch = blk % 12;
    const float* p = P + ((long long)b * 3 + maxidx[b]) * 196608;
    float t = thr[b];
    int base = ch * 16384;
    for (int l = 0; l < 64; ++l) {
        int idx = base + threadIdx.x + l * 256;
        if (p[idx] >= t) {
            int q = atomicAdd(&cntb[b], 1);
            if (q < 16) {
                int i = idx / 384, j = idx - i * 384;
                pos[b * 16 + q] = (i << 16) | j;
            }
        }
    }
}

// ------------- build nnz lists + den2 -------------
__global__ void build_nnz_kernel(const int* __restrict__ cntb, const int* __restrict__ pos,
                                 int* __restrict__ nnzc, int* __restrict__ jn,
                                 float* __restrict__ jv, float* __restrict__ den2)
{
    int b = threadIdx.x;
    if (b >= 16 || blockIdx.x != 0) return;
    int c = cntb[b]; if (c > 16) c = 16;
    for (int e = 0; e < c; ++e) {
        int pk = pos[b * 16 + e];
        int i = pk >> 16, j = pk & 0xFFFF;
        float val;
        if (i == j) val = 1.f;
        else {
            int rev = (j << 16) | i;
            int found = 0;
            for (int e2 = 0; e2 < c; ++e2) if (pos[b * 16 + e2] == rev) found = 1;
            val = 1.f + (float)found;
        }
        int r = b * 512 + i;
        int slot = nnzc[r];
        if (slot < 4) { jn[r * 4 + slot] = b * 512 + j; jv[r * 4 + slot] = val; }
        nnzc[r] = slot + 1;
        den2[r] += val;
    }
}

// ------------- GCN layer-1 fused sparse epilogue -> OUTL1 planes -------------
__global__ void gcn1_epilogue_kernel(const float* __restrict__ XW1, const float* __restrict__ b1,
                                     const float* __restrict__ den2, const int* __restrict__ cnt,
                                     const int* __restrict__ jn, const float* __restrict__ jv,
                                     unsigned short* __restrict__ outp)
{
    int m = blockIdx.x;
    int c = cnt[m]; if (c > 4) c = 4;
    float d2 = den2[m];
    int js[4]; float vs[4];
    for (int s = 0; s < c; ++s) { js[s] = jn[m * 4 + s]; vs[s] = jv[m * 4 + s]; }
    const float* xrow = XW1 + (long long)m * 768;
    #pragma unroll
    for (int l = 0; l < 3; ++l) {
        int d = threadIdx.x + l * 256;
        float ax = 0.f;
        for (int s = 0; s < c; ++s) ax += vs[s] * XW1[(long long)js[s] * 768 + d];
        float bb = b1[d];
        float v = fmaxf((ax + bb) / d2, 0.f) + xrow[d] + bb;
        unsigned short h, lo; cvt_split(v, h, lo);
        outp[(long long)m * 768 + d] = h;
        outp[6291456LL + (long long)m * 768 + d] = lo;
    }
}

}  // namespace

extern "C" void kernel_launch(void* const* d_in, const int* in_sizes, int n_in,
                              void* d_out, int out_size, void* d_ws, size_t ws_size,
                              hipStream_t stream) {
    const float* adj = (const float*)d_in[0];
    const float* inp = (const float*)d_in[1];
    const float* W0w = (const float*)d_in[3];
    const float* W0b = (const float*)d_in[4];
    const float* W1w = (const float*)d_in[5];
    const float* W1b = (const float*)d_in[6];
    const float* Cw  = (const float*)d_in[7];
    const float* Cbi = (const float*)d_in[8];
    const float* Lw  = (const float*)d_in[9];
    const float* Lb  = (const float*)d_in[10];
    const float* F1  = (const float*)d_in[11];
    const float* F2  = (const float*)d_in[12];
    const float* Qw  = (const float*)d_in[13];
    const float* Qb  = (const float*)d_in[14];
    const float* Kw  = (const float*)d_in[15];
    const float* Kbi = (const float*)d_in[16];
    float* out = (float*)d_out;

    if (ws_size < (size_t)TOTAL_FLOATS * sizeof(float)) {
        sentinel_kernel<<<dim3(1), dim3(64), 0, stream>>>(out);
        return;
    }

    float* W = (float*)d_ws;
    float*   DEN   = W + O_DEN;
    float*   DEN2  = W + O_DEN2;
    double*  SUMP  = (double*)(W + O_SUMP);
    float*   THR   = W + O_THR;
    int*     MIDX  = (int*)(W + O_MIDX);
    int*     CNT   = (int*)(W + O_CNT);
    int*     POS   = (int*)(W + O_POS);
    float2*  T2P   = (float2*)(W + O_T2P);
    int*     NNZC  = (int*)(W + O_NNZC);
    int*     NNZJ  = (int*)(W + O_NNZJ);
    float*   NNZV  = W + O_NNZV;
    float*   QKB   = W + O_QKB;

    unsigned short* INPP  = (unsigned short*)(W + O_X);
    float*          OUT0  = W + O_X;
    unsigned short* XCATp = (unsigned short*)(W + O_X);
    unsigned short* F1P   = (unsigned short*)(W + O_X);
    unsigned short* F2P   = (unsigned short*)(W + O_X + 589824);

    unsigned short* AXp    = (unsigned short*)(W + OZ);
    float*          AXW0f  = W + OZ + 6291456;
    float*          XW0f   = W + O_X + 6291456;           // X-region second half
    unsigned short* W0P    = (unsigned short*)(W + OZ + 12582912);
    unsigned short* ADJB   = (unsigned short*)(W + OZ + 13172736);
    unsigned short* CONVEp = (unsigned short*)(W + OZ);
    unsigned short* CwP    = (unsigned short*)(W + OZ + 6291456);
    unsigned short* LWPp   = (unsigned short*)(W + OZ + 7077888);
    unsigned short* QKp    = (unsigned short*)(W + OZ);
    float*          P      = W + OZ + 8388608;
    float*          XW1f   = W + OZ;
    unsigned short* OUTL1p = (unsigned short*)(W + OZ + 6291456);
    unsigned short* H1p    = (unsigned short*)(W + OZ);

    unsigned short* INPTB  = (unsigned short*)out;         // ph1 only
    unsigned short* QKwP   = (unsigned short*)out;
    unsigned short* W1P    = (unsigned short*)(out + 4718592);

    const float divs = sqrtf(512.0f);
    const int BIGN = 1 << 30;

    // ---- phase 1: GCN layer 0 ----
    convert_planes_kernel<<<dim3(6144), dim3(256), 0, stream>>>(inp, INPP, 6291456, 1572864);
    convert_planes_kernel<<<dim3(576), dim3(256), 0, stream>>>(W0w, W0P, 589824, 147456);
    convert_bf16_kernel<<<dim3(4096), dim3(256), 0, stream>>>(adj, ADJB, 1048576);
    transpose_bf16_kernel<<<dim3(8, 12, 16), dim3(256), 0, stream>>>(inp, INPTB);
    qkb_kernel<<<dim3(12), dim3(256), 0, stream>>>(Qb, Kbi, QKB);
    rowsum_kernel<<<dim3(8192), dim3(256), 0, stream>>>(adj, DEN, 512);
    // AX = adj @ inputs -> planes (1-pass bf16: error /denom(~257) ~3e-4)
    gemm_mfma_kernel<0, 3, 1, 1><<<dim3(6, 4, 16), dim3(256), 0, stream>>>(
        ADJB, INPTB, AXp, nullptr, 512, 768, 512, 512, 512, 768,
        262144LL, 393216LL, 393216LL, 1.f, 0, 0, 0, 6291456LL, BIGN);
    // XW0 = inp @ W0^T (z=0) and AXW0 = AX @ W0^T (z=1), merged via z-strides
    gemm_mfma_kernel<1, 3, 0, 0><<<dim3(6, 64, 2), dim3(256), 0, stream>>>(
        INPP, W0P, XW0f, nullptr, 8192, 768, 768, 768, 768, 768,
        25165824LL, 0, 12582912LL, 1.f, 0, 6291456LL, 589824LL, 0, BIGN);
    gcn_epilogue_kernel<<<dim3(24576), dim3(256), 0, stream>>>(AXW0f, XW0f, W0b, DEN, OUT0);

    // ---- weight conversions (d_out free after AX; Z tails free) ----
    convert_planes_kernel<<<dim3(768), dim3(256), 0, stream>>>(Cw, CwP, 786432, 196608);
    pad_lw_kernel<<<dim3(2304), dim3(256), 0, stream>>>(Lw, LWPp);
    convert_qkw_kernel<<<dim3(4608), dim3(256), 0, stream>>>(Qw, Kw, QKwP);
    convert_planes_kernel<<<dim3(1152), dim3(256), 0, stream>>>(W1w, W1P, 1179648, 294912);

    // ---- phase 2: conv + linearc -> xcat planes ----
    gemm_mfma_kernel<2, 2, 1, 0><<<dim3(6, 4, 16), dim3(256), 0, stream>>>(
        CwP, OUT0, CONVEp, Cbi, 512, 768, 1536, 1536, 0, 768,
        0, 393216LL, 393216LL, 1.f, 1, 786432LL, 0, 6291456LL, 766);
    gemm_mfma_kernel<3, 3, 1, 0><<<dim3(6, 64, 1), dim3(256), 0, stream>>>(
        CONVEp, LWPp, (void*)(XCATp + 768), Lb, 8192, 768, 768, 768, 768, 1536,
        0, 0, 0, 1.f, 0, 6291456LL, 589824LL, 12582912LL, BIGN);
    copy_concat_kernel<<<dim3(24576), dim3(256), 0, stream>>>(inp, XCATp);

    // ---- phase 3: merged QK projection + scores per head ----
    for (int h = 0; h < 3; ++h) {
        gemm_mfma_kernel<4, 3, 1, 0><<<dim3(8, 64, 1), dim3(256), 0, stream>>>(
            XCATp, QKwP + (long long)h * 1572864, QKp, QKB + h * 1024,
            8192, 1024, 1536, 1536, 1536, 1024,
            0, 0, 0, 1.f, 0, 12582912LL, 4718592LL, 8388608LL, BIGN);
        gemm_mfma_kernel<5, 3, 0, 0><<<dim3(3, 4, 16), dim3(256), 0, stream>>>(
            QKp, QKp + 512, P + (long long)h * 196608, nullptr,
            512, 384, 512, 1024, 1024, 384,
            524288LL, 524288LL, 589824LL, divs, 0, 8388608LL, 8388608LL, 0, BIGN);
    }

    // ---- softmax + decisions ----
    softmax_kernel<<<dim3(24576), dim3(128), 0, stream>>>(P);
    sums1_kernel<<<dim3(768), dim3(256), 0, stream>>>(P, SUMP);
    decide2_kernel<<<dim3(1), dim3(64), 0, stream>>>(SUMP, MIDX);
    top2a_kernel<<<dim3(512), dim3(256), 0, stream>>>(P, MIDX, T2P);
    top2b_kernel<<<dim3(16), dim3(64), 0, stream>>>(T2P, THR);
    init_nnz_kernel<<<dim3(32), dim3(256), 0, stream>>>(CNT, NNZC, DEN2);
    scan_thr_kernel<<<dim3(192), dim3(256), 0, stream>>>(P, MIDX, THR, CNT, POS);
    build_nnz_kernel<<<dim3(1), dim3(64), 0, stream>>>(CNT, POS, NNZC, NNZJ, NNZV, DEN2);

    // ---- phase 5: GCN layer 1 (sparse adj2) + fc ----
    gemm_mfma_kernel<6, 3, 0, 0><<<dim3(6, 64, 1), dim3(256), 0, stream>>>(
        XCATp, W1P, XW1f, nullptr, 8192, 768, 1536, 1536, 1536, 768,
        0, 0, 0, 1.f, 0, 12582912LL, 1179648LL, 0, BIGN);
    convert_planes_kernel<<<dim3(576), dim3(256), 0, stream>>>(F1, F1P, 589824, 147456);
    convert_planes_kernel<<<dim3(576), dim3(256), 0, stream>>>(F2, F2P, 589824, 147456);
    gcn1_epilogue_kernel<<<dim3(8192), dim3(256), 0, stream>>>(XW1f, W1b, DEN2, NNZC, NNZJ, NNZV, OUTL1p);
    gemm_mfma_kernel<7, 3, 1, 0><<<dim3(6, 64, 1), dim3(256), 0, stream>>>(
        OUTL1p, F1P, H1p, nullptr, 8192, 768, 768, 768, 768, 768,
        0, 0, 0, 1.f, 1, 6291456LL, 589824LL, 6291456LL, BIGN);
    gemm_mfma_kernel<8, 3, 0, 0><<<dim3(6, 64, 1), dim3(256), 0, stream>>>(
        H1p, F2P, out, nullptr, 8192, 768, 768, 768, 768, 768,
        0, 0, 0, 1.f, 0, 6291456LL, 589824LL, 0, BIGN);
}

// Round 5
// 1547.039 us; speedup vs baseline: 5.8421x; 1.0158x over previous
//
#include <hip/hip_runtime.h>
#include <math.h>

// B=16, N=512, D=768, Dh=1536, HEADS=3, keys>=384 masked.
// GEMM core: 128x128 tile, 32x32x16 MFMA, BK=16, FOUR LDS buffers (64KB),
// prefetch depth 3 with COUNTED s_waitcnt vmcnt(N) + raw s_barrier (T3/T4):
//   iter t: issue stage(t+3) -> vmcnt(12) -> barrier -> ds_read+MFMA -> barrier
// (round-4 lesson: __syncthreads() drains vmcnt(0) every step -> ~2150cyc/step
//  exposed latency vs ~400cyc compute; counted waits keep 3 stages in flight).
// Conv GEMM (BMODE=2, VALU-staged B) keeps the drain loop: its f32 loads make
// vmcnt counting unreliable.
// bf16x2 hi/lo split (3-pass) for precision-critical GEMMs; AX (adj@inp) runs
// 1-pass bf16 (error /denom~257 -> ~3e-4). launch_bounds(256,2) (round-3
// lesson: (256,4) on the unified 512-reg file spilled acc -> 3.2GB scratch).
//
// Arena (float units), 30539776 (~122.2 MB):
//  S [0,131072): scalars/lists (+QKB bias at 93184)
//  X [131072,+12582912): INPP planes (first half) + XW0f (second half) ->
//    OUT0 f32 -> XCATp planes -> F1P/F2P
//  Z = 12713984 (+17825792):
//   ph1: AXp[0,6.29M) AXW0f[6.29,12.58M) W0P[12.58,13.17M) ADJB[13.17,15.27M)
//   ph2: CONVEp[0,6.29M) CwP[6.29,7.08M) LWPp[7.08,7.67M)
//   ph3: QKp planes[0,8.39M) P f32[8.39,17.83M)
//   ph5: XW1f[0,6.29M) OUTL1p[6.29,12.58M) H1p[0,6.29M after XW1f dead)
//  d_out: ph1 INPTB bf16[0,3.15M); then QKwP[0,4.72M) W1P[4.72,5.9M); final out.

namespace {

constexpr long long O_DEN  = 0;
constexpr long long O_DEN2 = 8192;
constexpr long long O_SUMP = 16384;
constexpr long long O_THR  = 17920;
constexpr long long O_MIDX = 17936;
constexpr long long O_CNT  = 17952;
constexpr long long O_POS  = 17968;
constexpr long long O_T2P  = 18224;
constexpr long long O_NNZC = 19456;
constexpr long long O_NNZJ = 27648;
constexpr long long O_NNZV = 60416;
constexpr long long O_QKB  = 93184;   // 3072 floats

constexpr long long O_X    = 131072;
constexpr long long OZ     = 131072 + 12582912;          // 12713984
constexpr long long TOTAL_FLOATS = OZ + 17825792;        // 30539776

typedef short bf16x8 __attribute__((ext_vector_type(8)));
typedef float f32x4 __attribute__((ext_vector_type(4)));
typedef float f32x16 __attribute__((ext_vector_type(16)));

__global__ void sentinel_kernel(float* out) {
    if (threadIdx.x == 0 && blockIdx.x == 0) out[0] = 1.0e6f;
}

__device__ __forceinline__ unsigned short bf16rne(float f) {
    union { float x; unsigned u; } a; a.x = f;
    return (unsigned short)((a.u + 0x7FFFu + ((a.u >> 16) & 1u)) >> 16);
}

// RNE f32 -> bf16 hi + bf16(residual)
__device__ __forceinline__ void cvt_split(float f, unsigned short& h, unsigned short& l) {
    union { float x; unsigned u; } a; a.x = f;
    unsigned hb = (a.u + 0x7FFFu + ((a.u >> 16) & 1u)) & 0xFFFF0000u;
    h = (unsigned short)(hb >> 16);
    union { unsigned u; float x; } b; b.u = hb;
    float r = f - b.x;
    union { float x; unsigned u; } c; c.x = r;
    l = (unsigned short)((c.u + 0x7FFFu + ((c.u >> 16) & 1u)) >> 16);
}

// async 16B global->LDS (lds dest: wave-uniform base + lane*16)
__device__ __forceinline__ void gl_lds16(const unsigned short* g, unsigned short* l) {
    __builtin_amdgcn_global_load_lds(
        (const __attribute__((address_space(1))) unsigned int*)g,
        (__attribute__((address_space(3))) unsigned int*)l,
        16, 0, 0);
}

// ---------------- f32 -> planes converter ----------------
__global__ void convert_planes_kernel(const float* __restrict__ src, unsigned short* __restrict__ dst,
                                      long long loOff, long long n4) {
    long long idx = (long long)blockIdx.x * 256 + threadIdx.x;
    if (idx >= n4) return;
    float4 v = ((const float4*)src)[idx];
    unsigned short h0,h1,h2,h3,l0,l1,l2,l3;
    cvt_split(v.x,h0,l0); cvt_split(v.y,h1,l1); cvt_split(v.z,h2,l2); cvt_split(v.w,h3,l3);
    uint2 hp, lp;
    hp.x = (unsigned)h0 | ((unsigned)h1 << 16); hp.y = (unsigned)h2 | ((unsigned)h3 << 16);
    lp.x = (unsigned)l0 | ((unsigned)l1 << 16); lp.y = (unsigned)l2 | ((unsigned)l3 << 16);
    *(uint2*)&dst[idx * 4] = hp;
    *(uint2*)&dst[loOff + idx * 4] = lp;
}

// ---------------- f32 -> single bf16 plane ----------------
__global__ void convert_bf16_kernel(const float* __restrict__ src, unsigned short* __restrict__ dst,
                                    long long n4) {
    long long idx = (long long)blockIdx.x * 256 + threadIdx.x;
    if (idx >= n4) return;
    float4 v = ((const float4*)src)[idx];
    ushort4 o;
    o.x = bf16rne(v.x); o.y = bf16rne(v.y); o.z = bf16rne(v.z); o.w = bf16rne(v.w);
    *(ushort4*)&dst[idx * 4] = o;
}

// ------------- inp [z][512][768] f32 -> inp^T [z][768][512] bf16 -------------
__global__ void transpose_bf16_kernel(const float* __restrict__ inp, unsigned short* __restrict__ dst) {
    __shared__ float T[64][65];
    const int z = blockIdx.z;
    const int i0 = blockIdx.x * 64, d0 = blockIdx.y * 64;
    const float* src = inp + (long long)z * 393216;
    unsigned short* dz = dst + (long long)z * 393216;
    const int cl = threadIdx.x & 63, rl = threadIdx.x >> 6;
    #pragma unroll 4
    for (int e = 0; e < 16; ++e) {
        int il = e * 4 + rl;
        T[il][cl] = src[(long long)(i0 + il) * 768 + d0 + cl];
    }
    __syncthreads();
    #pragma unroll 4
    for (int e = 0; e < 16; ++e) {
        int dl = e * 4 + rl;
        dz[(long long)(d0 + dl) * 512 + i0 + cl] = bf16rne(T[cl][dl]);
    }
}

// ---------------- pad linearc_w [768,766] -> planes [768,768] ----------------
__global__ void pad_lw_kernel(const float* __restrict__ Lw, unsigned short* __restrict__ Lp) {
    int idx = blockIdx.x * 256 + threadIdx.x;  // 589824
    int n = idx / 768, k = idx - n * 768;
    float v = (k < 766) ? Lw[n * 766 + k] : 0.f;
    unsigned short h, l; cvt_split(v, h, l);
    Lp[idx] = h; Lp[589824 + idx] = l;
}

// ---------------- stacked QK weights -> planes [3][1024][1536] ----------------
__global__ void convert_qkw_kernel(const float* __restrict__ Qw, const float* __restrict__ Kw,
                                   unsigned short* __restrict__ dst) {
    long long idx = (long long)blockIdx.x * 256 + threadIdx.x;  // < 1179648
    if (idx >= 1179648) return;
    long long e = idx * 4;
    int h = (int)(e / 1572864);
    int rem = (int)(e - (long long)h * 1572864);
    int row = rem / 1536, k = rem - row * 1536;
    const float* src = (row < 512) ? (Qw + ((long long)(h * 512 + row) * 1536 + k))
                                   : (Kw + ((long long)(h * 512 + row - 512) * 1536 + k));
    float4 v = *(const float4*)src;
    unsigned short h0,h1,h2,h3,l0,l1,l2,l3;
    cvt_split(v.x,h0,l0); cvt_split(v.y,h1,l1); cvt_split(v.z,h2,l2); cvt_split(v.w,h3,l3);
    uint2 hp, lp;
    hp.x = (unsigned)h0 | ((unsigned)h1 << 16); hp.y = (unsigned)h2 | ((unsigned)h3 << 16);
    lp.x = (unsigned)l0 | ((unsigned)l1 << 16); lp.y = (unsigned)l2 | ((unsigned)l3 << 16);
    *(uint2*)&dst[e] = hp;
    *(uint2*)&dst[4718592 + e] = lp;
}

// ---------------- stacked QK bias [3][1024] ----------------
__global__ void qkb_kernel(const float* __restrict__ Qb, const float* __restrict__ Kb,
                           float* __restrict__ qkb) {
    int i = blockIdx.x * 256 + threadIdx.x;
    if (i >= 3072) return;
    int h = i >> 10, r = i & 1023;
    qkb[i] = (r < 512) ? Qb[h * 512 + r] : Kb[h * 512 + r - 512];
}

// ===== MFMA GEMM, 128x128 tile, 32x32x16, BK=16, 4-buf counted pipeline =====
// A: always bf16 planes, async (lo at +aLo; ONEPASS -> hi only).
// BMODE: 3=NT planes async (counted-vmcnt pipeline), 2=conv f32 window
//        (bias by m, drain-at-barrier loop).
// CMODE: 0=f32, 1=planes (lo at +cLo). n>=Nreal -> 0.
template<int TAG, int BMODE, int CMODE, int ONEPASS>
__global__ __launch_bounds__(256, 2)
void gemm_mfma_kernel(const unsigned short* __restrict__ Au, const void* __restrict__ Bv,
                      void* __restrict__ Cv, const float* __restrict__ bias,
                      int M, int N, int K, int lda, int ldb, int ldc,
                      long long sA, long long sB, long long sC,
                      float divd, int relu, long long aLo,
                      long long bLo, long long cLo, int Nreal)
{
    __shared__ __align__(16) unsigned short AhS[4][2][128][8];
    __shared__ __align__(16) unsigned short BhS[4][2][128][8];
    __shared__ __align__(16) unsigned short AlS[ONEPASS ? 1 : 4][2][128][8];
    __shared__ __align__(16) unsigned short BlS[ONEPASS ? 1 : 4][2][128][8];

    const int z = blockIdx.z;
    const int tid = threadIdx.x;
    const int m0 = blockIdx.y * 128, n0 = blockIdx.x * 128;
    const int lane = tid & 63, wave = tid >> 6;
    const int wm = (wave & 1) * 64, wn = (wave >> 1) * 64;
    const int lk = lane >> 5, lm = lane & 31;

    const unsigned short* A = Au + z * sA;
    const float* Bf = (const float*)Bv + z * sB;
    const unsigned short* Bu = (const unsigned short*)Bv + z * sB;
    float* Cf = (float*)Cv + z * sC;
    unsigned short* Cu = (unsigned short*)Cv + z * sC;

    f32x16 acc[2][2];
    #pragma unroll
    for (int i = 0; i < 2; ++i)
        #pragma unroll
        for (int j = 0; j < 2; ++j)
            #pragma unroll
            for (int r = 0; r < 16; ++r) acc[i][j][r] = 0.f;

    // BMODE=2 staging indices
    const int c_nlo = tid & 31;
    const int c_khalf = (tid >> 5) & 1;
    const int c_n = wave * 32 + c_nlo;          // 0..127

    auto stage = [&](int kk, int b) {
        // A (128 x 16, hi[+lo] planes): per wave 2 issues (1-pass) / same q-map
        #pragma unroll
        for (int l = 0; l < (ONEPASS ? 1 : 2); ++l) {
            const int q = l * 4 + wave;
            const int kc = (q & 3) >> 1, rg = q & 1;
            const unsigned short* g = A + (long long)(m0 + rg * 64 + lane) * lda + kk + kc * 8;
            unsigned short* d = &AhS[b][kc][rg * 64][0];
            if constexpr (!ONEPASS) {
                if (q >> 2) { g += aLo; d = &AlS[b][kc][rg * 64][0]; }
            }
            gl_lds16(g, d);
        }
        if constexpr (BMODE == 3) {
            #pragma unroll
            for (int l = 0; l < (ONEPASS ? 1 : 2); ++l) {
                const int q = l * 4 + wave;
                const int kc = (q & 3) >> 1, rg = q & 1;
                const unsigned short* g = Bu + (long long)(n0 + rg * 64 + lane) * ldb + kk + kc * 8;
                unsigned short* d = &BhS[b][kc][rg * 64][0];
                if constexpr (!ONEPASS) {
                    if (q >> 2) { g += bLo; d = &BlS[b][kc][rg * 64][0]; }
                }
                gl_lds16(g, d);
            }
        } else {
            // conv window: thread covers (n=c_n, kgroup = khalf+2r), 4 consecutive k
            // -> one uint2 per plane (~4-way bank aliasing).
            #pragma unroll
            for (int r = 0; r < 2; ++r) {
                const int kgroup = c_khalf + 2 * r;   // 0..3
                const int k4 = kgroup * 4;
                float vv[4];
                #pragma unroll
                for (int e = 0; e < 4; ++e) {
                    const int kg = kk + k4 + e;
                    const int ii = kg / 3, k3 = kg - ii * 3;
                    // edge cols >=768 read into next row; only feed C cols >=Nreal (zeroed)
                    vv[e] = Bf[(long long)ii * 768 + (n0 + c_n) + k3];
                }
                unsigned short h0,h1,h2,h3,l0,l1,l2,l3;
                cvt_split(vv[0],h0,l0); cvt_split(vv[1],h1,l1);
                cvt_split(vv[2],h2,l2); cvt_split(vv[3],h3,l3);
                uint2 hp, lp;
                hp.x = (unsigned)h0 | ((unsigned)h1 << 16);
                hp.y = (unsigned)h2 | ((unsigned)h3 << 16);
                lp.x = (unsigned)l0 | ((unsigned)l1 << 16);
                lp.y = (unsigned)l2 | ((unsigned)l3 << 16);
                const int kc = kgroup >> 1, kp = (kgroup & 1) * 4;
                *(uint2*)&BhS[b][kc][c_n][kp] = hp;
                *(uint2*)&BlS[b][kc][c_n][kp] = lp;
            }
        }
    };

    auto compute = [&](int b) {
        bf16x8 ah[2], bh[2];
        #pragma unroll
        for (int i = 0; i < 2; ++i) ah[i] = *(const bf16x8*)&AhS[b][lk][wm + i * 32 + lm][0];
        #pragma unroll
        for (int j = 0; j < 2; ++j) bh[j] = *(const bf16x8*)&BhS[b][lk][wn + j * 32 + lm][0];
        if constexpr (ONEPASS) {
            #pragma unroll
            for (int i = 0; i < 2; ++i)
                #pragma unroll
                for (int j = 0; j < 2; ++j)
                    acc[i][j] = __builtin_amdgcn_mfma_f32_32x32x16_bf16(ah[i], bh[j], acc[i][j], 0, 0, 0);
        } else {
            bf16x8 al[2], bl[2];
            #pragma unroll
            for (int i = 0; i < 2; ++i) al[i] = *(const bf16x8*)&AlS[b][lk][wm + i * 32 + lm][0];
            #pragma unroll
            for (int j = 0; j < 2; ++j) bl[j] = *(const bf16x8*)&BlS[b][lk][wn + j * 32 + lm][0];
            #pragma unroll
            for (int i = 0; i < 2; ++i)
                #pragma unroll
                for (int j = 0; j < 2; ++j) {
                    acc[i][j] = __builtin_amdgcn_mfma_f32_32x32x16_bf16(ah[i], bh[j], acc[i][j], 0, 0, 0);
                    acc[i][j] = __builtin_amdgcn_mfma_f32_32x32x16_bf16(ah[i], bl[j], acc[i][j], 0, 0, 0);
                    acc[i][j] = __builtin_amdgcn_mfma_f32_32x32x16_bf16(al[i], bh[j], acc[i][j], 0, 0, 0);
                }
        }
    };

    const int nt = K >> 4;
    if constexpr (BMODE == 3) {
        // ---- counted-vmcnt pipeline, prefetch depth 3 ----
        stage(0, 0);
        if (nt > 1) stage(16, 1);
        if (nt > 2) stage(32, 2);
        for (int t = 0; t < nt; ++t) {
            if (t + 3 < nt) stage((t + 3) << 4, (t + 3) & 3);
            const int d = nt - 1 - t;
            if constexpr (ONEPASS) {
                if (d >= 3)      { asm volatile("s_waitcnt vmcnt(6)" ::: "memory"); }
                else if (d == 2) { asm volatile("s_waitcnt vmcnt(4)" ::: "memory"); }
                else if (d == 1) { asm volatile("s_waitcnt vmcnt(2)" ::: "memory"); }
                else             { asm volatile("s_waitcnt vmcnt(0)" ::: "memory"); }
            } else {
                if (d >= 3)      { asm volatile("s_waitcnt vmcnt(12)" ::: "memory"); }
                else if (d == 2) { asm volatile("s_waitcnt vmcnt(8)" ::: "memory"); }
                else if (d == 1) { asm volatile("s_waitcnt vmcnt(4)" ::: "memory"); }
                else             { asm volatile("s_waitcnt vmcnt(0)" ::: "memory"); }
            }
            __builtin_amdgcn_sched_barrier(0);
            __builtin_amdgcn_s_barrier();     // all waves' stage(t) landed
            __builtin_amdgcn_sched_barrier(0);
            compute(t & 3);
            __builtin_amdgcn_sched_barrier(0);
            __builtin_amdgcn_s_barrier();     // all waves done reading buf t&3
        }
    } else {
        // ---- drain loop (conv: VALU-staged B, uncountable vmem) ----
        stage(0, 0);
        __syncthreads();
        for (int t = 0; t < nt; ++t) {
            if (t + 1 < nt) stage((t + 1) << 4, (t + 1) & 3);
            compute(t & 3);
            __syncthreads();
        }
    }
    // ---- epilogue: C/D layout col=lane&31, row=(reg&3)+8*(reg>>2)+4*(lane>>5) ----
    #pragma unroll
    for (int i = 0; i < 2; ++i) {
        #pragma unroll
        for (int j = 0; j < 2; ++j) {
            #pragma unroll
            for (int reg = 0; reg < 16; ++reg) {
                const int m = m0 + wm + i * 32 + (reg & 3) + 8 * (reg >> 2) + 4 * lk;
                const int n = n0 + wn + j * 32 + lm;
                float v = acc[i][j][reg];
                if (divd != 1.f) v = v / divd;
                if (bias) v += bias[BMODE == 2 ? m : n];
                if (relu) v = fmaxf(v, 0.f);
                if (n >= Nreal) v = 0.f;
                if constexpr (CMODE == 1) {
                    unsigned short h, l; cvt_split(v, h, l);
                    Cu[(long long)m * ldc + n] = h;
                    Cu[cLo + (long long)m * ldc + n] = l;
                } else {
                    Cf[(long long)m * ldc + n] = v;
                }
            }
        }
    }
}

// ---------------- row sum (+1) for adj ----------------
__global__ void rowsum_kernel(const float* __restrict__ A, float* __restrict__ out, int ncols) {
    const float* row = A + (long long)blockIdx.x * ncols;
    float s = 0.f;
    for (int j = threadIdx.x; j < ncols; j += 256) s += row[j];
    __shared__ float red[256];
    red[threadIdx.x] = s;
    __syncthreads();
    for (int st = 128; st > 0; st >>= 1) {
        if (threadIdx.x < st) red[threadIdx.x] += red[threadIdx.x + st];
        __syncthreads();
    }
    if (threadIdx.x == 0) out[blockIdx.x] = red[0] + 1.0f;
}

// ------------- GCN layer-0 epilogue -------------
__global__ void gcn_epilogue_kernel(const float* __restrict__ axw, const float* __restrict__ xw,
                                    const float* __restrict__ bias, const float* __restrict__ denom,
                                    float* __restrict__ out)
{
    long long idx = (long long)blockIdx.x * 256 + threadIdx.x;  // 8192*768
    int m = (int)(idx / 768);
    int d = (int)(idx - (long long)m * 768);
    float bb = bias[d];
    float v = (axw[idx] + bb) / denom[m];
    out[idx] = fmaxf(v, 0.f) + xw[idx] + bb;
}

// ------------- inputs -> XCAT planes cols 0..767 -------------
__global__ void copy_concat_kernel(const float* __restrict__ inp, unsigned short* __restrict__ xcat)
{
    long long idx = (long long)blockIdx.x * 256 + threadIdx.x;  // 8192*768
    int m = (int)(idx / 768);
    int d = (int)(idx - (long long)m * 768);
    unsigned short h, l; cvt_split(inp[idx], h, l);
    xcat[(long long)m * 1536 + d] = h;
    xcat[12582912LL + (long long)m * 1536 + d] = l;
}

// ------------- row softmax over 384 stored cols (ld=384) -------------
__global__ void softmax_kernel(float* __restrict__ P)
{
    float* row = P + (long long)blockIdx.x * 384;
    const int t = threadIdx.x;  // 128
    float v0 = row[t], v1 = row[t + 128], v2 = row[t + 256];
    float m = fmaxf(v0, fmaxf(v1, v2));
    #pragma unroll
    for (int off = 32; off > 0; off >>= 1) m = fmaxf(m, __shfl_down(m, off));
    __shared__ float redm[2];
    if ((t & 63) == 0) redm[t >> 6] = m;
    __syncthreads();
    m = fmaxf(redm[0], redm[1]);
    float e0 = expf(v0 - m), e1 = expf(v1 - m), e2 = expf(v2 - m);
    float s = e0 + e1 + e2;
    #pragma unroll
    for (int off = 32; off > 0; off >>= 1) s += __shfl_down(s, off);
    __shared__ float reds[2];
    if ((t & 63) == 0) reds[t >> 6] = s;
    __syncthreads();
    s = reds[0] + reds[1];
    row[t] = e0 / s;
    row[t + 128] = e1 / s;
    row[t + 256] = e2 / s;
}

// ------------- sums stage 1 (f64 partials) -------------
__global__ void sums1_kernel(const float* __restrict__ P, double* __restrict__ sump)
{
    int blk = blockIdx.x;
    int bh = blk >> 4, ch = blk & 15;
    const float* p = P + (long long)bh * 196608 + ch * 12288;
    double s = 0.0;
    for (int i = threadIdx.x; i < 12288; i += 256) s += (double)p[i];
    __shared__ double red[256];
    red[threadIdx.x] = s;
    __syncthreads();
    for (int st = 128; st > 0; st >>= 1) {
        if (threadIdx.x < st) red[threadIdx.x] += red[threadIdx.x + st];
        __syncthreads();
    }
    if (threadIdx.x == 0) sump[blk] = red[0];
}

// ------------- sums stage 2 + head decision -------------
__global__ void decide2_kernel(const double* __restrict__ sump, int* __restrict__ maxidx)
{
    __shared__ double s48[48];
    int t = threadIdx.x;
    if (t < 48) {
        double s = 0.0;
        for (int i = 0; i < 16; ++i) s += sump[t * 16 + i];
        s48[t] = s;
    }
    __syncthreads();
    if (t == 0) {
        float s[16][3], prob[16][3];
        for (int b = 0; b < 16; ++b)
            for (int h = 0; h < 3; ++h) s[b][h] = (float)s48[b * 3 + h];
        for (int h = 0; h < 3; ++h) {
            float m = -1e30f;
            for (int b = 0; b < 16; ++b) m = fmaxf(m, s[b][h]);
            float e[16]; float Z = 0.f;
            for (int b = 0; b < 16; ++b) { e[b] = expf(s[b][h] - m); Z += e[b]; }
            for (int b = 0; b < 16; ++b) prob[b][h] = e[b] / Z;
        }
        for (int b = 0; b < 16; ++b) {
            int best = 0; float bv = prob[b][0];
            for (int h = 1; h < 3; ++h) if (prob[b][h] > bv) { bv = prob[b][h]; best = h; }
            maxidx[b] = best;
        }
    }
}

// ------------- top2 stage 1 -------------
__global__ void top2a_kernel(const float* __restrict__ P, const int* __restrict__ maxidx,
                             float2* __restrict__ t2p)
{
    int blk = blockIdx.x;
    int b = blk >> 5, ch = blk & 31;
    const float* p = P + ((long long)b * 3 + maxidx[b]) * 196608 + ch * 6144;
    float m1 = -1e30f, m2 = -1e30f;
    for (int i = threadIdx.x; i < 6144; i += 256) {
        float v = p[i];
        if (v > m1) { m2 = m1; m1 = v; }
        else if (v > m2) { m2 = v; }
    }
    __shared__ float r1[256], r2[256];
    r1[threadIdx.x] = m1; r2[threadIdx.x] = m2;
    __syncthreads();
    if (threadIdx.x == 0) {
        float M1 = -1e30f, M2 = -1e30f;
        for (int i = 0; i < 256; ++i) {
            float a = r1[i], c = r2[i];
            if (a > M1) { M2 = M1; M1 = a; } else if (a > M2) { M2 = a; }
            if (c > M1) { M2 = M1; M1 = c; } else if (c > M2) { M2 = c; }
        }
        t2p[blk] = make_float2(M1, M2);
    }
}

// ------------- top2 stage 2 -------------
__global__ void top2b_kernel(const float2* __restrict__ t2p, float* __restrict__ thr)
{
    int b = blockIdx.x;
    if (threadIdx.x != 0) return;
    float M1 = -1e30f, M2 = -1e30f;
    for (int i = 0; i < 32; ++i) {
        float2 v = t2p[b * 32 + i];
        if (v.x > M1) { M2 = M1; M1 = v.x; } else if (v.x > M2) { M2 = v.x; }
        if (v.y > M1) { M2 = M1; M1 = v.y; } else if (v.y > M2) { M2 = v.y; }
    }
    thr[b] = M2;
}

// ------------- init nnz state -------------
__global__ void init_nnz_kernel(int* __restrict__ cntb, int* __restrict__ nnzc,
                                float* __restrict__ den2)
{
    int idx = blockIdx.x * 256 + threadIdx.x;
    if (idx < 16) cntb[idx] = 0;
    if (idx < 8192) { nnzc[idx] = 0; den2[idx] = 1.f; }
}

// ------------- scan P for p>=thr (exact >= tie semantics) -------------
__global__ void scan_thr_kernel(const float* __restrict__ P, const int* __restrict__ maxidx,
                                const float* __restrict__ thr, int* __restrict__ cntb,
                                int* __restrict__ pos)
{
    int blk = blockIdx.x;            // 16*12
    int b = blk / 12, ch = blk % 12;
    const float* p = P + ((long long)b * 3 + maxidx[b]) * 196608;
    float t = thr[b];
    int base = ch * 16384;
    for (int l = 0; l < 64; ++l) {
        int idx = base + threadIdx.x + l * 256;
        if (p[idx] >= t) {
            int q = atomicAdd(&cntb[b], 1);
            if (q < 16) {
                int i = idx / 384, j = idx - i * 384;
                pos[b * 16 + q] = (i << 16) | j;
            }
        }
    }
}

// ------------- build nnz lists + den2 -------------
__global__ void build_nnz_kernel(const int* __restrict__ cntb, const int* __restrict__ pos,
                                 int* __restrict__ nnzc, int* __restrict__ jn,
                                 float* __restrict__ jv, float* __restrict__ den2)
{
    int b = threadIdx.x;
    if (b >= 16 || blockIdx.x != 0) return;
    int c = cntb[b]; if (c > 16) c = 16;
    for (int e = 0; e < c; ++e) {
        int pk = pos[b * 16 + e];
        int i = pk >> 16, j = pk & 0xFFFF;
        float val;
        if (i == j) val = 1.f;
        else {
            int rev = (j << 16) | i;
            int found = 0;
            for (int e2 = 0; e2 < c; ++e2) if (pos[b * 16 + e2] == rev) found = 1;
            val = 1.f + (float)found;
        }
        int r = b * 512 + i;
        int slot = nnzc[r];
        if (slot < 4) { jn[r * 4 + slot] = b * 512 + j; jv[r * 4 + slot] = val; }
        nnzc[r] = slot + 1;
        den2[r] += val;
    }
}

// ------------- GCN layer-1 fused sparse epilogue -> OUTL1 planes -------------
__global__ void gcn1_epilogue_kernel(const float* __restrict__ XW1, const float* __restrict__ b1,
                                     const float* __restrict__ den2, const int* __restrict__ cnt,
                                     const int* __restrict__ jn, const float* __restrict__ jv,
                                     unsigned short* __restrict__ outp)
{
    int m = blockIdx.x;
    int c = cnt[m]; if (c > 4) c = 4;
    float d2 = den2[m];
    int js[4]; float vs[4];
    for (int s = 0; s < c; ++s) { js[s] = jn[m * 4 + s]; vs[s] = jv[m * 4 + s]; }
    const float* xrow = XW1 + (long long)m * 768;
    #pragma unroll
    for (int l = 0; l < 3; ++l) {
        int d = threadIdx.x + l * 256;
        float ax = 0.f;
        for (int s = 0; s < c; ++s) ax += vs[s] * XW1[(long long)js[s] * 768 + d];
        float bb = b1[d];
        float v = fmaxf((ax + bb) / d2, 0.f) + xrow[d] + bb;
        unsigned short h, lo; cvt_split(v, h, lo);
        outp[(long long)m * 768 + d] = h;
        outp[6291456LL + (long long)m * 768 + d] = lo;
    }
}

}  // namespace

extern "C" void kernel_launch(void* const* d_in, const int* in_sizes, int n_in,
                              void* d_out, int out_size, void* d_ws, size_t ws_size,
                              hipStream_t stream) {
    const float* adj = (const float*)d_in[0];
    const float* inp = (const float*)d_in[1];
    const float* W0w = (const float*)d_in[3];
    const float* W0b = (const float*)d_in[4];
    const float* W1w = (const float*)d_in[5];
    const float* W1b = (const float*)d_in[6];
    const float* Cw  = (const float*)d_in[7];
    const float* Cbi = (const float*)d_in[8];
    const float* Lw  = (const float*)d_in[9];
    const float* Lb  = (const float*)d_in[10];
    const float* F1  = (const float*)d_in[11];
    const float* F2  = (const float*)d_in[12];
    const float* Qw  = (const float*)d_in[13];
    const float* Qb  = (const float*)d_in[14];
    const float* Kw  = (const float*)d_in[15];
    const float* Kbi = (const float*)d_in[16];
    float* out = (float*)d_out;

    if (ws_size < (size_t)TOTAL_FLOATS * sizeof(float)) {
        sentinel_kernel<<<dim3(1), dim3(64), 0, stream>>>(out);
        return;
    }

    float* W = (float*)d_ws;
    float*   DEN   = W + O_DEN;
    float*   DEN2  = W + O_DEN2;
    double*  SUMP  = (double*)(W + O_SUMP);
    float*   THR   = W + O_THR;
    int*     MIDX  = (int*)(W + O_MIDX);
    int*     CNT   = (int*)(W + O_CNT);
    int*     POS   = (int*)(W + O_POS);
    float2*  T2P   = (float2*)(W + O_T2P);
    int*     NNZC  = (int*)(W + O_NNZC);
    int*     NNZJ  = (int*)(W + O_NNZJ);
    float*   NNZV  = W + O_NNZV;
    float*   QKB   = W + O_QKB;

    unsigned short* INPP  = (unsigned short*)(W + O_X);
    float*          OUT0  = W + O_X;
    unsigned short* XCATp = (unsigned short*)(W + O_X);
    unsigned short* F1P   = (unsigned short*)(W + O_X);
    unsigned short* F2P   = (unsigned short*)(W + O_X + 589824);

    unsigned short* AXp    = (unsigned short*)(W + OZ);
    float*          AXW0f  = W + OZ + 6291456;
    float*          XW0f   = W + O_X + 6291456;           // X-region second half
    unsigned short* W0P    = (unsigned short*)(W + OZ + 12582912);
    unsigned short* ADJB   = (unsigned short*)(W + OZ + 13172736);
    unsigned short* CONVEp = (unsigned short*)(W + OZ);
    unsigned short* CwP    = (unsigned short*)(W + OZ + 6291456);
    unsigned short* LWPp   = (unsigned short*)(W + OZ + 7077888);
    unsigned short* QKp    = (unsigned short*)(W + OZ);
    float*          P      = W + OZ + 8388608;
    float*          XW1f   = W + OZ;
    unsigned short* OUTL1p = (unsigned short*)(W + OZ + 6291456);
    unsigned short* H1p    = (unsigned short*)(W + OZ);

    unsigned short* INPTB  = (unsigned short*)out;         // ph1 only
    unsigned short* QKwP   = (unsigned short*)out;
    unsigned short* W1P    = (unsigned short*)(out + 4718592);

    const float divs = sqrtf(512.0f);
    const int BIGN = 1 << 30;

    // ---- phase 1: GCN layer 0 ----
    convert_planes_kernel<<<dim3(6144), dim3(256), 0, stream>>>(inp, INPP, 6291456, 1572864);
    convert_planes_kernel<<<dim3(576), dim3(256), 0, stream>>>(W0w, W0P, 589824, 147456);
    convert_bf16_kernel<<<dim3(4096), dim3(256), 0, stream>>>(adj, ADJB, 1048576);
    transpose_bf16_kernel<<<dim3(8, 12, 16), dim3(256), 0, stream>>>(inp, INPTB);
    qkb_kernel<<<dim3(12), dim3(256), 0, stream>>>(Qb, Kbi, QKB);
    rowsum_kernel<<<dim3(8192), dim3(256), 0, stream>>>(adj, DEN, 512);
    // AX = adj @ inputs -> planes (1-pass bf16: error /denom(~257) ~3e-4)
    gemm_mfma_kernel<0, 3, 1, 1><<<dim3(6, 4, 16), dim3(256), 0, stream>>>(
        ADJB, INPTB, AXp, nullptr, 512, 768, 512, 512, 512, 768,
        262144LL, 393216LL, 393216LL, 1.f, 0, 0, 0, 6291456LL, BIGN);
    // XW0 = inp @ W0^T (z=0) and AXW0 = AX @ W0^T (z=1), merged via z-strides
    gemm_mfma_kernel<1, 3, 0, 0><<<dim3(6, 64, 2), dim3(256), 0, stream>>>(
        INPP, W0P, XW0f, nullptr, 8192, 768, 768, 768, 768, 768,
        25165824LL, 0, 12582912LL, 1.f, 0, 6291456LL, 589824LL, 0, BIGN);
    gcn_epilogue_kernel<<<dim3(24576), dim3(256), 0, stream>>>(AXW0f, XW0f, W0b, DEN, OUT0);

    // ---- weight conversions (d_out free after AX; Z tails free) ----
    convert_planes_kernel<<<dim3(768), dim3(256), 0, stream>>>(Cw, CwP, 786432, 196608);
    pad_lw_kernel<<<dim3(2304), dim3(256), 0, stream>>>(Lw, LWPp);
    convert_qkw_kernel<<<dim3(4608), dim3(256), 0, stream>>>(Qw, Kw, QKwP);
    convert_planes_kernel<<<dim3(1152), dim3(256), 0, stream>>>(W1w, W1P, 1179648, 294912);

    // ---- phase 2: conv + linearc -> xcat planes ----
    gemm_mfma_kernel<2, 2, 1, 0><<<dim3(6, 4, 16), dim3(256), 0, stream>>>(
        CwP, OUT0, CONVEp, Cbi, 512, 768, 1536, 1536, 0, 768,
        0, 393216LL, 393216LL, 1.f, 1, 786432LL, 0, 6291456LL, 766);
    gemm_mfma_kernel<3, 3, 1, 0><<<dim3(6, 64, 1), dim3(256), 0, stream>>>(
        CONVEp, LWPp, (void*)(XCATp + 768), Lb, 8192, 768, 768, 768, 768, 1536,
        0, 0, 0, 1.f, 0, 6291456LL, 589824LL, 12582912LL, BIGN);
    copy_concat_kernel<<<dim3(24576), dim3(256), 0, stream>>>(inp, XCATp);

    // ---- phase 3: merged QK projection + scores per head ----
    for (int h = 0; h < 3; ++h) {
        gemm_mfma_kernel<4, 3, 1, 0><<<dim3(8, 64, 1), dim3(256), 0, stream>>>(
            XCATp, QKwP + (long long)h * 1572864, QKp, QKB + h * 1024,
            8192, 1024, 1536, 1536, 1536, 1024,
            0, 0, 0, 1.f, 0, 12582912LL, 4718592LL, 8388608LL, BIGN);
        gemm_mfma_kernel<5, 3, 0, 0><<<dim3(3, 4, 16), dim3(256), 0, stream>>>(
            QKp, QKp + 512, P + (long long)h * 196608, nullptr,
            512, 384, 512, 1024, 1024, 384,
            524288LL, 524288LL, 589824LL, divs, 0, 8388608LL, 8388608LL, 0, BIGN);
    }

    // ---- softmax + decisions ----
    softmax_kernel<<<dim3(24576), dim3(128), 0, stream>>>(P);
    sums1_kernel<<<dim3(768), dim3(256), 0, stream>>>(P, SUMP);
    decide2_kernel<<<dim3(1), dim3(64), 0, stream>>>(SUMP, MIDX);
    top2a_kernel<<<dim3(512), dim3(256), 0, stream>>>(P, MIDX, T2P);
    top2b_kernel<<<dim3(16), dim3(64), 0, stream>>>(T2P, THR);
    init_nnz_kernel<<<dim3(32), dim3(256), 0, stream>>>(CNT, NNZC, DEN2);
    scan_thr_kernel<<<dim3(192), dim3(256), 0, stream>>>(P, MIDX, THR, CNT, POS);
    build_nnz_kernel<<<dim3(1), dim3(64), 0, stream>>>(CNT, POS, NNZC, NNZJ, NNZV, DEN2);

    // ---- phase 5: GCN layer 1 (sparse adj2) + fc ----
    gemm_mfma_kernel<6, 3, 0, 0><<<dim3(6, 64, 1), dim3(256), 0, stream>>>(
        XCATp, W1P, XW1f, nullptr, 8192, 768, 1536, 1536, 1536, 768,
        0, 0, 0, 1.f, 0, 12582912LL, 1179648LL, 0, BIGN);
    convert_planes_kernel<<<dim3(576), dim3(256), 0, stream>>>(F1, F1P, 589824, 147456);
    convert_planes_kernel<<<dim3(576), dim3(256), 0, stream>>>(F2, F2P, 589824, 147456);
    gcn1_epilogue_kernel<<<dim3(8192), dim3(256), 0, stream>>>(XW1f, W1b, DEN2, NNZC, NNZJ, NNZV, OUTL1p);
    gemm_mfma_kernel<7, 3, 1, 0><<<dim3(6, 64, 1), dim3(256), 0, stream>>>(
        OUTL1p, F1P, H1p, nullptr, 8192, 768, 768, 768, 768, 768,
        0, 0, 0, 1.f, 1, 6291456LL, 589824LL, 6291456LL, BIGN);
    gemm_mfma_kernel<8, 3, 0, 0><<<dim3(6, 64, 1), dim3(256), 0, stream>>>(
        H1p, F2P, out, nullptr, 8192, 768, 768, 768, 768, 768,
        0, 0, 0, 1.f, 0, 6291456LL, 589824LL, 0, BIGN);
}

// Round 6
// 1149.642 us; speedup vs baseline: 7.8615x; 1.3457x over previous
//
#include <hip/hip_runtime.h>
#include <math.h>

// B=16, N=512, D=768, Dh=1536, HEADS=3, keys>=384 masked.
// GEMM core: 128x128 tile, 32x32x16 MFMA, BK=32, double-buffered LDS (64KB),
// counted s_waitcnt vmcnt(LPS) pipeline (depth 1; round-5 showed deeper is null).
// ROUND-6 FIX: staging was 64x16B row-scattered requests per wave-load (TA
// request-rate bound ~1000cyc/block-step, invariant across r4/r5 sync changes).
// Now LDS rows are [128][32] (64B/row); a wave's DMA covers 16 rows x full 64B
// (4 lanes/row, k-chunk XOR-permuted by c^((row>>1)&3)) -> 16 coalesced 64B
// segments per load (4x request cut). Read side applies the same XOR
// (slot = kc ^ ((lm>>1)&3)) -> all 8 bank-quads covered, b128 floor.
// Plus bijective XCD-chunk blockIdx swizzle (T1/m204) for A-panel L2 reuse.
// bf16x2 hi/lo split (3-pass) for precision-critical GEMMs; AX (adj@inp) runs
// 1-pass bf16 (error /denom~257 -> ~3e-4). launch_bounds(256,2) (round-3
// lesson: (256,4) on the unified 512-reg file spilled acc -> 3.2GB scratch).
//
// Arena (float units), 30539776 (~122.2 MB):
//  S [0,131072): scalars/lists (+QKB bias at 93184)
//  X [131072,+12582912): INPP planes (first half) + XW0f (second half) ->
//    OUT0 f32 -> XCATp planes -> F1P/F2P
//  Z = 12713984 (+17825792):
//   ph1: AXp[0,6.29M) AXW0f[6.29,12.58M) W0P[12.58,13.17M) ADJB[13.17,15.27M)
//   ph2: CONVEp[0,6.29M) CwP[6.29,7.08M) LWPp[7.08,7.67M)
//   ph3: QKp planes[0,8.39M) P f32[8.39,17.83M)
//   ph5: XW1f[0,6.29M) OUTL1p[6.29,12.58M) H1p[0,6.29M after XW1f dead)
//  d_out: ph1 INPTB bf16[0,3.15M); then QKwP[0,4.72M) W1P[4.72,5.9M); final out.

namespace {

constexpr long long O_DEN  = 0;
constexpr long long O_DEN2 = 8192;
constexpr long long O_SUMP = 16384;
constexpr long long O_THR  = 17920;
constexpr long long O_MIDX = 17936;
constexpr long long O_CNT  = 17952;
constexpr long long O_POS  = 17968;
constexpr long long O_T2P  = 18224;
constexpr long long O_NNZC = 19456;
constexpr long long O_NNZJ = 27648;
constexpr long long O_NNZV = 60416;
constexpr long long O_QKB  = 93184;   // 3072 floats

constexpr long long O_X    = 131072;
constexpr long long OZ     = 131072 + 12582912;          // 12713984
constexpr long long TOTAL_FLOATS = OZ + 17825792;        // 30539776

typedef short bf16x8 __attribute__((ext_vector_type(8)));
typedef float f32x4 __attribute__((ext_vector_type(4)));
typedef float f32x16 __attribute__((ext_vector_type(16)));

__global__ void sentinel_kernel(float* out) {
    if (threadIdx.x == 0 && blockIdx.x == 0) out[0] = 1.0e6f;
}

__device__ __forceinline__ unsigned short bf16rne(float f) {
    union { float x; unsigned u; } a; a.x = f;
    return (unsigned short)((a.u + 0x7FFFu + ((a.u >> 16) & 1u)) >> 16);
}

// RNE f32 -> bf16 hi + bf16(residual)
__device__ __forceinline__ void cvt_split(float f, unsigned short& h, unsigned short& l) {
    union { float x; unsigned u; } a; a.x = f;
    unsigned hb = (a.u + 0x7FFFu + ((a.u >> 16) & 1u)) & 0xFFFF0000u;
    h = (unsigned short)(hb >> 16);
    union { unsigned u; float x; } b; b.u = hb;
    float r = f - b.x;
    union { float x; unsigned u; } c; c.x = r;
    l = (unsigned short)((c.u + 0x7FFFu + ((c.u >> 16) & 1u)) >> 16);
}

// async 16B global->LDS (lds dest: wave-uniform base + lane*16)
__device__ __forceinline__ void gl_lds16(const unsigned short* g, unsigned short* l) {
    __builtin_amdgcn_global_load_lds(
        (const __attribute__((address_space(1))) unsigned int*)g,
        (__attribute__((address_space(3))) unsigned int*)l,
        16, 0, 0);
}

// ---------------- f32 -> planes converter ----------------
__global__ void convert_planes_kernel(const float* __restrict__ src, unsigned short* __restrict__ dst,
                                      long long loOff, long long n4) {
    long long idx = (long long)blockIdx.x * 256 + threadIdx.x;
    if (idx >= n4) return;
    float4 v = ((const float4*)src)[idx];
    unsigned short h0,h1,h2,h3,l0,l1,l2,l3;
    cvt_split(v.x,h0,l0); cvt_split(v.y,h1,l1); cvt_split(v.z,h2,l2); cvt_split(v.w,h3,l3);
    uint2 hp, lp;
    hp.x = (unsigned)h0 | ((unsigned)h1 << 16); hp.y = (unsigned)h2 | ((unsigned)h3 << 16);
    lp.x = (unsigned)l0 | ((unsigned)l1 << 16); lp.y = (unsigned)l2 | ((unsigned)l3 << 16);
    *(uint2*)&dst[idx * 4] = hp;
    *(uint2*)&dst[loOff + idx * 4] = lp;
}

// ---------------- f32 -> single bf16 plane ----------------
__global__ void convert_bf16_kernel(const float* __restrict__ src, unsigned short* __restrict__ dst,
                                    long long n4) {
    long long idx = (long long)blockIdx.x * 256 + threadIdx.x;
    if (idx >= n4) return;
    float4 v = ((const float4*)src)[idx];
    ushort4 o;
    o.x = bf16rne(v.x); o.y = bf16rne(v.y); o.z = bf16rne(v.z); o.w = bf16rne(v.w);
    *(ushort4*)&dst[idx * 4] = o;
}

// ------------- inp [z][512][768] f32 -> inp^T [z][768][512] bf16 -------------
__global__ void transpose_bf16_kernel(const float* __restrict__ inp, unsigned short* __restrict__ dst) {
    __shared__ float T[64][65];
    const int z = blockIdx.z;
    const int i0 = blockIdx.x * 64, d0 = blockIdx.y * 64;
    const float* src = inp + (long long)z * 393216;
    unsigned short* dz = dst + (long long)z * 393216;
    const int cl = threadIdx.x & 63, rl = threadIdx.x >> 6;
    #pragma unroll 4
    for (int e = 0; e < 16; ++e) {
        int il = e * 4 + rl;
        T[il][cl] = src[(long long)(i0 + il) * 768 + d0 + cl];
    }
    __syncthreads();
    #pragma unroll 4
    for (int e = 0; e < 16; ++e) {
        int dl = e * 4 + rl;
        dz[(long long)(d0 + dl) * 512 + i0 + cl] = bf16rne(T[cl][dl]);
    }
}

// ---------------- pad linearc_w [768,766] -> planes [768,768] ----------------
__global__ void pad_lw_kernel(const float* __restrict__ Lw, unsigned short* __restrict__ Lp) {
    int idx = blockIdx.x * 256 + threadIdx.x;  // 589824
    int n = idx / 768, k = idx - n * 768;
    float v = (k < 766) ? Lw[n * 766 + k] : 0.f;
    unsigned short h, l; cvt_split(v, h, l);
    Lp[idx] = h; Lp[589824 + idx] = l;
}

// ---------------- stacked QK weights -> planes [3][1024][1536] ----------------
__global__ void convert_qkw_kernel(const float* __restrict__ Qw, const float* __restrict__ Kw,
                                   unsigned short* __restrict__ dst) {
    long long idx = (long long)blockIdx.x * 256 + threadIdx.x;  // < 1179648
    if (idx >= 1179648) return;
    long long e = idx * 4;
    int h = (int)(e / 1572864);
    int rem = (int)(e - (long long)h * 1572864);
    int row = rem / 1536, k = rem - row * 1536;
    const float* src = (row < 512) ? (Qw + ((long long)(h * 512 + row) * 1536 + k))
                                   : (Kw + ((long long)(h * 512 + row - 512) * 1536 + k));
    float4 v = *(const float4*)src;
    unsigned short h0,h1,h2,h3,l0,l1,l2,l3;
    cvt_split(v.x,h0,l0); cvt_split(v.y,h1,l1); cvt_split(v.z,h2,l2); cvt_split(v.w,h3,l3);
    uint2 hp, lp;
    hp.x = (unsigned)h0 | ((unsigned)h1 << 16); hp.y = (unsigned)h2 | ((unsigned)h3 << 16);
    lp.x = (unsigned)l0 | ((unsigned)l1 << 16); lp.y = (unsigned)l2 | ((unsigned)l3 << 16);
    *(uint2*)&dst[e] = hp;
    *(uint2*)&dst[4718592 + e] = lp;
}

// ---------------- stacked QK bias [3][1024] ----------------
__global__ void qkb_kernel(const float* __restrict__ Qb, const float* __restrict__ Kb,
                           float* __restrict__ qkb) {
    int i = blockIdx.x * 256 + threadIdx.x;
    if (i >= 3072) return;
    int h = i >> 10, r = i & 1023;
    qkb[i] = (r < 512) ? Qb[h * 512 + r] : Kb[h * 512 + r - 512];
}

// ===== MFMA GEMM, 128x128 tile, 32x32x16, BK=32, coalesced swizzled staging =====
// A: always bf16 planes, async (lo at +aLo; ONEPASS -> hi only).
// BMODE: 3=NT planes async (counted-vmcnt dbuf), 2=conv f32 window
//        (bias by m, drain-at-barrier loop; B VALU-staged, linear ds_writes).
// CMODE: 0=f32, 1=planes (lo at +cLo). n>=Nreal -> 0.
// LDS tile [128][32] ushort (64B rows). Swizzle: LDS[row][slot c] holds global
// k-chunk (c ^ ((row>>1)&3)); read slot = kc ^ ((lm>>1)&3).
template<int TAG, int BMODE, int CMODE, int ONEPASS>
__global__ __launch_bounds__(256, 2)
void gemm_mfma_kernel(const unsigned short* __restrict__ Au, const void* __restrict__ Bv,
                      void* __restrict__ Cv, const float* __restrict__ bias,
                      int M, int N, int K, int lda, int ldb, int ldc,
                      long long sA, long long sB, long long sC,
                      float divd, int relu, long long aLo,
                      long long bLo, long long cLo, int Nreal)
{
    __shared__ __align__(16) unsigned short AhS[2][128][32];
    __shared__ __align__(16) unsigned short BhS[2][128][32];
    __shared__ __align__(16) unsigned short AlS[2][128][32];
    __shared__ __align__(16) unsigned short BlS[2][128][32];

    // ---- bijective XCD-chunk swizzle (T1/m204) ----
    const int gx = gridDim.x, gy = gridDim.y;
    const int nwg = gx * gy * gridDim.z;
    const int lin = blockIdx.x + gx * (blockIdx.y + gy * blockIdx.z);
    const int q8 = nwg >> 3, r8 = nwg & 7;
    const int xcd = lin & 7, sidx = lin >> 3;
    const int nl = (xcd < r8) ? xcd * (q8 + 1) + sidx : r8 * (q8 + 1) + (xcd - r8) * q8 + sidx;
    const int bx = nl % gx;
    const int t1 = nl / gx;
    const int by = t1 % gy;
    const int z  = t1 / gy;

    const int tid = threadIdx.x;
    const int m0 = by * 128, n0 = bx * 128;
    const int lane = tid & 63, wave = tid >> 6;
    const int wm = (wave & 1) * 64, wn = (wave >> 1) * 64;
    const int lk = lane >> 5, lm = lane & 31;
    const int sxor = (lm >> 1) & 3;                 // read-side slot XOR

    const unsigned short* A = Au + z * sA;
    const float* Bf = (const float*)Bv + z * sB;
    const unsigned short* Bu = (const unsigned short*)Bv + z * sB;
    float* Cf = (float*)Cv + z * sC;
    unsigned short* Cu = (unsigned short*)Cv + z * sC;

    f32x16 acc[2][2];
    #pragma unroll
    for (int i = 0; i < 2; ++i)
        #pragma unroll
        for (int j = 0; j < 2; ++j)
            #pragma unroll
            for (int r = 0; r < 16; ++r) acc[i][j][r] = 0.f;

    // staging map: chunk index j = v*256 + wave*64 + lane; row=j>>2, c=j&3.
    // source k-chunk = c ^ ((row>>1)&3); per-row 4 lanes cover full 64B line.
    auto stage = [&](int kk, int b) {
        #pragma unroll
        for (int v = 0; v < 2; ++v) {
            const int j0 = v * 256 + (wave << 6);   // uniform chunk base
            const int row0 = j0 >> 2;               // uniform LDS row base
            const int j = j0 + lane;
            const int row = j >> 2, c = j & 3;
            const int kch = c ^ ((row >> 1) & 3);
            const long long aoff = (long long)(m0 + row) * lda + kk + kch * 8;
            gl_lds16(A + aoff, &AhS[b][row0][0]);
            if constexpr (!ONEPASS) gl_lds16(A + aLo + aoff, &AlS[b][row0][0]);
            if constexpr (BMODE == 3) {
                const long long boff = (long long)(n0 + row) * ldb + kk + kch * 8;
                gl_lds16(Bu + boff, &BhS[b][row0][0]);
                if constexpr (!ONEPASS) gl_lds16(Bu + bLo + boff, &BlS[b][row0][0]);
            }
        }
        if constexpr (BMODE == 2) {
            // conv window B: VALU-staged, linear 16B ds_writes (conflict-free).
            #pragma unroll
            for (int v = 0; v < 2; ++v) {
                const int j = v * 256 + tid;
                const int n = j >> 2, c = j & 3;
                const int kch = c ^ ((n >> 1) & 3);
                const int k8 = kk + kch * 8;
                unsigned short hh[8], ll[8];
                #pragma unroll
                for (int e = 0; e < 8; ++e) {
                    const int kg = k8 + e;
                    const int ii = kg / 3, k3 = kg - ii * 3;
                    // edge cols >=768 read into next row; only feed C cols >=Nreal (zeroed)
                    cvt_split(Bf[(long long)ii * 768 + (n0 + n) + k3], hh[e], ll[e]);
                }
                uint4 hp, lp;
                hp.x = (unsigned)hh[0] | ((unsigned)hh[1] << 16);
                hp.y = (unsigned)hh[2] | ((unsigned)hh[3] << 16);
                hp.z = (unsigned)hh[4] | ((unsigned)hh[5] << 16);
                hp.w = (unsigned)hh[6] | ((unsigned)hh[7] << 16);
                lp.x = (unsigned)ll[0] | ((unsigned)ll[1] << 16);
                lp.y = (unsigned)ll[2] | ((unsigned)ll[3] << 16);
                lp.z = (unsigned)ll[4] | ((unsigned)ll[5] << 16);
                lp.w = (unsigned)ll[6] | ((unsigned)ll[7] << 16);
                *(uint4*)&BhS[b][n][c * 8] = hp;
                *(uint4*)&BlS[b][n][c * 8] = lp;
            }
        }
    };

    auto compute = [&](int b) {
        #pragma unroll
        for (int ks = 0; ks < 2; ++ks) {
            const int kc = ks * 2 + lk;
            const int sl = (kc ^ sxor) * 8;
            bf16x8 ah[2], bh[2];
            #pragma unroll
            for (int i = 0; i < 2; ++i) ah[i] = *(const bf16x8*)&AhS[b][wm + i * 32 + lm][sl];
            #pragma unroll
            for (int j = 0; j < 2; ++j) bh[j] = *(const bf16x8*)&BhS[b][wn + j * 32 + lm][sl];
            if constexpr (ONEPASS) {
                #pragma unroll
                for (int i = 0; i < 2; ++i)
                    #pragma unroll
                    for (int j = 0; j < 2; ++j)
                        acc[i][j] = __builtin_amdgcn_mfma_f32_32x32x16_bf16(ah[i], bh[j], acc[i][j], 0, 0, 0);
            } else {
                bf16x8 al[2], bl[2];
                #pragma unroll
                for (int i = 0; i < 2; ++i) al[i] = *(const bf16x8*)&AlS[b][wm + i * 32 + lm][sl];
                #pragma unroll
                for (int j = 0; j < 2; ++j) bl[j] = *(const bf16x8*)&BlS[b][wn + j * 32 + lm][sl];
                #pragma unroll
                for (int i = 0; i < 2; ++i)
                    #pragma unroll
                    for (int j = 0; j < 2; ++j) {
                        acc[i][j] = __builtin_amdgcn_mfma_f32_32x32x16_bf16(ah[i], bh[j], acc[i][j], 0, 0, 0);
                        acc[i][j] = __builtin_amdgcn_mfma_f32_32x32x16_bf16(ah[i], bl[j], acc[i][j], 0, 0, 0);
                        acc[i][j] = __builtin_amdgcn_mfma_f32_32x32x16_bf16(al[i], bh[j], acc[i][j], 0, 0, 0);
                    }
            }
        }
    };

    const int nt = K >> 5;
    if constexpr (BMODE == 3) {
        // ---- counted-vmcnt double-buffer pipeline ----
        stage(0, 0);
        for (int t = 0; t < nt; ++t) {
            const bool more = (t + 1 < nt);
            if (more) stage((t + 1) << 5, (t + 1) & 1);
            if (more) {
                if constexpr (ONEPASS) { asm volatile("s_waitcnt vmcnt(4)" ::: "memory"); }
                else                   { asm volatile("s_waitcnt vmcnt(8)" ::: "memory"); }
            } else {
                asm volatile("s_waitcnt vmcnt(0)" ::: "memory");
            }
            __builtin_amdgcn_sched_barrier(0);
            __builtin_amdgcn_s_barrier();     // all waves' stage(t) landed
            __builtin_amdgcn_sched_barrier(0);
            compute(t & 1);
            __builtin_amdgcn_sched_barrier(0);
            __builtin_amdgcn_s_barrier();     // all waves done reading buf t&1
        }
    } else {
        // ---- drain loop (conv: VALU-staged B, uncountable vmem) ----
        stage(0, 0);
        __syncthreads();
        for (int t = 0; t < nt; ++t) {
            if (t + 1 < nt) stage((t + 1) << 5, (t + 1) & 1);
            compute(t & 1);
            __syncthreads();
        }
    }
    // ---- epilogue: C/D layout col=lane&31, row=(reg&3)+8*(reg>>2)+4*(lane>>5) ----
    #pragma unroll
    for (int i = 0; i < 2; ++i) {
        #pragma unroll
        for (int j = 0; j < 2; ++j) {
            #pragma unroll
            for (int reg = 0; reg < 16; ++reg) {
                const int m = m0 + wm + i * 32 + (reg & 3) + 8 * (reg >> 2) + 4 * lk;
                const int n = n0 + wn + j * 32 + lm;
                float v = acc[i][j][reg];
                if (divd != 1.f) v = v / divd;
                if (bias) v += bias[BMODE == 2 ? m : n];
                if (relu) v = fmaxf(v, 0.f);
                if (n >= Nreal) v = 0.f;
                if constexpr (CMODE == 1) {
                    unsigned short h, l; cvt_split(v, h, l);
                    Cu[(long long)m * ldc + n] = h;
                    Cu[cLo + (long long)m * ldc + n] = l;
                } else {
                    Cf[(long long)m * ldc + n] = v;
                }
            }
        }
    }
}

// ---------------- row sum (+1) for adj ----------------
__global__ void rowsum_kernel(const float* __restrict__ A, float* __restrict__ out, int ncols) {
    const float* row = A + (long long)blockIdx.x * ncols;
    float s = 0.f;
    for (int j = threadIdx.x; j < ncols; j += 256) s += row[j];
    __shared__ float red[256];
    red[threadIdx.x] = s;
    __syncthreads();
    for (int st = 128; st > 0; st >>= 1) {
        if (threadIdx.x < st) red[threadIdx.x] += red[threadIdx.x + st];
        __syncthreads();
    }
    if (threadIdx.x == 0) out[blockIdx.x] = red[0] + 1.0f;
}

// ------------- GCN layer-0 epilogue -------------
__global__ void gcn_epilogue_kernel(const float* __restrict__ axw, const float* __restrict__ xw,
                                    const float* __restrict__ bias, const float* __restrict__ denom,
                                    float* __restrict__ out)
{
    long long idx = (long long)blockIdx.x * 256 + threadIdx.x;  // 8192*768
    int m = (int)(idx / 768);
    int d = (int)(idx - (long long)m * 768);
    float bb = bias[d];
    float v = (axw[idx] + bb) / denom[m];
    out[idx] = fmaxf(v, 0.f) + xw[idx] + bb;
}

// ------------- inputs -> XCAT planes cols 0..767 -------------
__global__ void copy_concat_kernel(const float* __restrict__ inp, unsigned short* __restrict__ xcat)
{
    long long idx = (long long)blockIdx.x * 256 + threadIdx.x;  // 8192*768
    int m = (int)(idx / 768);
    int d = (int)(idx - (long long)m * 768);
    unsigned short h, l; cvt_split(inp[idx], h, l);
    xcat[(long long)m * 1536 + d] = h;
    xcat[12582912LL + (long long)m * 1536 + d] = l;
}

// ------------- row softmax over 384 stored cols (ld=384) -------------
__global__ void softmax_kernel(float* __restrict__ P)
{
    float* row = P + (long long)blockIdx.x * 384;
    const int t = threadIdx.x;  // 128
    float v0 = row[t], v1 = row[t + 128], v2 = row[t + 256];
    float m = fmaxf(v0, fmaxf(v1, v2));
    #pragma unroll
    for (int off = 32; off > 0; off >>= 1) m = fmaxf(m, __shfl_down(m, off));
    __shared__ float redm[2];
    if ((t & 63) == 0) redm[t >> 6] = m;
    __syncthreads();
    m = fmaxf(redm[0], redm[1]);
    float e0 = expf(v0 - m), e1 = expf(v1 - m), e2 = expf(v2 - m);
    float s = e0 + e1 + e2;
    #pragma unroll
    for (int off = 32; off > 0; off >>= 1) s += __shfl_down(s, off);
    __shared__ float reds[2];
    if ((t & 63) == 0) reds[t >> 6] = s;
    __syncthreads();
    s = reds[0] + reds[1];
    row[t] = e0 / s;
    row[t + 128] = e1 / s;
    row[t + 256] = e2 / s;
}

// ------------- sums stage 1 (f64 partials) -------------
__global__ void sums1_kernel(const float* __restrict__ P, double* __restrict__ sump)
{
    int blk = blockIdx.x;
    int bh = blk >> 4, ch = blk & 15;
    const float* p = P + (long long)bh * 196608 + ch * 12288;
    double s = 0.0;
    for (int i = threadIdx.x; i < 12288; i += 256) s += (double)p[i];
    __shared__ double red[256];
    red[threadIdx.x] = s;
    __syncthreads();
    for (int st = 128; st > 0; st >>= 1) {
        if (threadIdx.x < st) red[threadIdx.x] += red[threadIdx.x + st];
        __syncthreads();
    }
    if (threadIdx.x == 0) sump[blk] = red[0];
}

// ------------- sums stage 2 + head decision -------------
__global__ void decide2_kernel(const double* __restrict__ sump, int* __restrict__ maxidx)
{
    __shared__ double s48[48];
    int t = threadIdx.x;
    if (t < 48) {
        double s = 0.0;
        for (int i = 0; i < 16; ++i) s += sump[t * 16 + i];
        s48[t] = s;
    }
    __syncthreads();
    if (t == 0) {
        float s[16][3], prob[16][3];
        for (int b = 0; b < 16; ++b)
            for (int h = 0; h < 3; ++h) s[b][h] = (float)s48[b * 3 + h];
        for (int h = 0; h < 3; ++h) {
            float m = -1e30f;
            for (int b = 0; b < 16; ++b) m = fmaxf(m, s[b][h]);
            float e[16]; float Z = 0.f;
            for (int b = 0; b < 16; ++b) { e[b] = expf(s[b][h] - m); Z += e[b]; }
            for (int b = 0; b < 16; ++b) prob[b][h] = e[b] / Z;
        }
        for (int b = 0; b < 16; ++b) {
            int best = 0; float bv = prob[b][0];
            for (int h = 1; h < 3; ++h) if (prob[b][h] > bv) { bv = prob[b][h]; best = h; }
            maxidx[b] = best;
        }
    }
}

// ------------- top2 stage 1 -------------
__global__ void top2a_kernel(const float* __restrict__ P, const int* __restrict__ maxidx,
                             float2* __restrict__ t2p)
{
    int blk = blockIdx.x;
    int b = blk >> 5, ch = blk & 31;
    const float* p = P + ((long long)b * 3 + maxidx[b]) * 196608 + ch * 6144;
    float m1 = -1e30f, m2 = -1e30f;
    for (int i = threadIdx.x; i < 6144; i += 256) {
        float v = p[i];
        if (v > m1) { m2 = m1; m1 = v; }
        else if (v > m2) { m2 = v; }
    }
    __shared__ float r1[256], r2[256];
    r1[threadIdx.x] = m1; r2[threadIdx.x] = m2;
    __syncthreads();
    if (threadIdx.x == 0) {
        float M1 = -1e30f, M2 = -1e30f;
        for (int i = 0; i < 256; ++i) {
            float a = r1[i], c = r2[i];
            if (a > M1) { M2 = M1; M1 = a; } else if (a > M2) { M2 = a; }
            if (c > M1) { M2 = M1; M1 = c; } else if (c > M2) { M2 = c; }
        }
        t2p[blk] = make_float2(M1, M2);
    }
}

// ------------- top2 stage 2 -------------
__global__ void top2b_kernel(const float2* __restrict__ t2p, float* __restrict__ thr)
{
    int b = blockIdx.x;
    if (threadIdx.x != 0) return;
    float M1 = -1e30f, M2 = -1e30f;
    for (int i = 0; i < 32; ++i) {
        float2 v = t2p[b * 32 + i];
        if (v.x > M1) { M2 = M1; M1 = v.x; } else if (v.x > M2) { M2 = v.x; }
        if (v.y > M1) { M2 = M1; M1 = v.y; } else if (v.y > M2) { M2 = v.y; }
    }
    thr[b] = M2;
}

// ------------- init nnz state -------------
__global__ void init_nnz_kernel(int* __restrict__ cntb, int* __restrict__ nnzc,
                                float* __restrict__ den2)
{
    int idx = blockIdx.x * 256 + threadIdx.x;
    if (idx < 16) cntb[idx] = 0;
    if (idx < 8192) { nnzc[idx] = 0; den2[idx] = 1.f; }
}

// ------------- scan P for p>=thr (exact >= tie semantics) -------------
__global__ void scan_thr_kernel(const float* __restrict__ P, const int* __restrict__ maxidx,
                                const float* __restrict__ thr, int* __restrict__ cntb,
                                int* __restrict__ pos)
{
    int blk = blockIdx.x;            // 16*12
    int b = blk / 12, ch = blk % 12;
    const float* p = P + ((long long)b * 3 + maxidx[b]) * 196608;
    float t = thr[b];
    int base = ch * 16384;
    for (int l = 0; l < 64; ++l) {
        int idx = base + threadIdx.x + l * 256;
        if (p[idx] >= t) {
            int q = atomicAdd(&cntb[b], 1);
            if (q < 16) {
                int i = idx / 384, j = idx - i * 384;
                pos[b * 16 + q] = (i << 16) | j;
            }
        }
    }
}

// ------------- build nnz lists + den2 -------------
__global__ void build_nnz_kernel(const int* __restrict__ cntb, const int* __restrict__ pos,
                                 int* __restrict__ nnzc, int* __restrict__ jn,
                                 float* __restrict__ jv, float* __restrict__ den2)
{
    int b = threadIdx.x;
    if (b >= 16 || blockIdx.x != 0) return;
    int c = cntb[b]; if (c > 16) c = 16;
    for (int e = 0; e < c; ++e) {
        int pk = pos[b * 16 + e];
        int i = pk >> 16, j = pk & 0xFFFF;
        float val;
        if (i == j) val = 1.f;
        else {
            int rev = (j << 16) | i;
            int found = 0;
            for (int e2 = 0; e2 < c; ++e2) if (pos[b * 16 + e2] == rev) found = 1;
            val = 1.f + (float)found;
        }
        int r = b * 512 + i;
        int slot = nnzc[r];
        if (slot < 4) { jn[r * 4 + slot] = b * 512 + j; jv[r * 4 + slot] = val; }
        nnzc[r] = slot + 1;
        den2[r] += val;
    }
}

// ------------- GCN layer-1 fused sparse epilogue -> OUTL1 planes -------------
__global__ void gcn1_epilogue_kernel(const float* __restrict__ XW1, const float* __restrict__ b1,
                                     const float* __restrict__ den2, const int* __restrict__ cnt,
                                     const int* __restrict__ jn, const float* __restrict__ jv,
                                     unsigned short* __restrict__ outp)
{
    int m = blockIdx.x;
    int c = cnt[m]; if (c > 4) c = 4;
    float d2 = den2[m];
    int js[4]; float vs[4];
    for (int s = 0; s < c; ++s) { js[s] = jn[m * 4 + s]; vs[s] = jv[m * 4 + s]; }
    const float* xrow = XW1 + (long long)m * 768;
    #pragma unroll
    for (int l = 0; l < 3; ++l) {
        int d = threadIdx.x + l * 256;
        float ax = 0.f;
        for (int s = 0; s < c; ++s) ax += vs[s] * XW1[(long long)js[s] * 768 + d];
        float bb = b1[d];
        float v = fmaxf((ax + bb) / d2, 0.f) + xrow[d] + bb;
        unsigned short h, lo; cvt_split(v, h, lo);
        outp[(long long)m * 768 + d] = h;
        outp[6291456LL + (long long)m * 768 + d] = lo;
    }
}

}  // namespace

extern "C" void kernel_launch(void* const* d_in, const int* in_sizes, int n_in,
                              void* d_out, int out_size, void* d_ws, size_t ws_size,
                              hipStream_t stream) {
    const float* adj = (const float*)d_in[0];
    const float* inp = (const float*)d_in[1];
    const float* W0w = (const float*)d_in[3];
    const float* W0b = (const float*)d_in[4];
    const float* W1w = (const float*)d_in[5];
    const float* W1b = (const float*)d_in[6];
    const float* Cw  = (const float*)d_in[7];
    const float* Cbi = (const float*)d_in[8];
    const float* Lw  = (const float*)d_in[9];
    const float* Lb  = (const float*)d_in[10];
    const float* F1  = (const float*)d_in[11];
    const float* F2  = (const float*)d_in[12];
    const float* Qw  = (const float*)d_in[13];
    const float* Qb  = (const float*)d_in[14];
    const float* Kw  = (const float*)d_in[15];
    const float* Kbi = (const float*)d_in[16];
    float* out = (float*)d_out;

    if (ws_size < (size_t)TOTAL_FLOATS * sizeof(float)) {
        sentinel_kernel<<<dim3(1), dim3(64), 0, stream>>>(out);
        return;
    }

    float* W = (float*)d_ws;
    float*   DEN   = W + O_DEN;
    float*   DEN2  = W + O_DEN2;
    double*  SUMP  = (double*)(W + O_SUMP);
    float*   THR   = W + O_THR;
    int*     MIDX  = (int*)(W + O_MIDX);
    int*     CNT   = (int*)(W + O_CNT);
    int*     POS   = (int*)(W + O_POS);
    float2*  T2P   = (float2*)(W + O_T2P);
    int*     NNZC  = (int*)(W + O_NNZC);
    int*     NNZJ  = (int*)(W + O_NNZJ);
    float*   NNZV  = W + O_NNZV;
    float*   QKB   = W + O_QKB;

    unsigned short* INPP  = (unsigned short*)(W + O_X);
    float*          OUT0  = W + O_X;
    unsigned short* XCATp = (unsigned short*)(W + O_X);
    unsigned short* F1P   = (unsigned short*)(W + O_X);
    unsigned short* F2P   = (unsigned short*)(W + O_X + 589824);

    unsigned short* AXp    = (unsigned short*)(W + OZ);
    float*          AXW0f  = W + OZ + 6291456;
    float*          XW0f   = W + O_X + 6291456;           // X-region second half
    unsigned short* W0P    = (unsigned short*)(W + OZ + 12582912);
    unsigned short* ADJB   = (unsigned short*)(W + OZ + 13172736);
    unsigned short* CONVEp = (unsigned short*)(W + OZ);
    unsigned short* CwP    = (unsigned short*)(W + OZ + 6291456);
    unsigned short* LWPp   = (unsigned short*)(W + OZ + 7077888);
    unsigned short* QKp    = (unsigned short*)(W + OZ);
    float*          P      = W + OZ + 8388608;
    float*          XW1f   = W + OZ;
    unsigned short* OUTL1p = (unsigned short*)(W + OZ + 6291456);
    unsigned short* H1p    = (unsigned short*)(W + OZ);

    unsigned short* INPTB  = (unsigned short*)out;         // ph1 only
    unsigned short* QKwP   = (unsigned short*)out;
    unsigned short* W1P    = (unsigned short*)(out + 4718592);

    const float divs = sqrtf(512.0f);
    const int BIGN = 1 << 30;

    // ---- phase 1: GCN layer 0 ----
    convert_planes_kernel<<<dim3(6144), dim3(256), 0, stream>>>(inp, INPP, 6291456, 1572864);
    convert_planes_kernel<<<dim3(576), dim3(256), 0, stream>>>(W0w, W0P, 589824, 147456);
    convert_bf16_kernel<<<dim3(4096), dim3(256), 0, stream>>>(adj, ADJB, 1048576);
    transpose_bf16_kernel<<<dim3(8, 12, 16), dim3(256), 0, stream>>>(inp, INPTB);
    qkb_kernel<<<dim3(12), dim3(256), 0, stream>>>(Qb, Kbi, QKB);
    rowsum_kernel<<<dim3(8192), dim3(256), 0, stream>>>(adj, DEN, 512);
    // AX = adj @ inputs -> planes (1-pass bf16: error /denom(~257) ~3e-4)
    gemm_mfma_kernel<0, 3, 1, 1><<<dim3(6, 4, 16), dim3(256), 0, stream>>>(
        ADJB, INPTB, AXp, nullptr, 512, 768, 512, 512, 512, 768,
        262144LL, 393216LL, 393216LL, 1.f, 0, 0, 0, 6291456LL, BIGN);
    // XW0 = inp @ W0^T (z=0) and AXW0 = AX @ W0^T (z=1), merged via z-strides
    gemm_mfma_kernel<1, 3, 0, 0><<<dim3(6, 64, 2), dim3(256), 0, stream>>>(
        INPP, W0P, XW0f, nullptr, 8192, 768, 768, 768, 768, 768,
        25165824LL, 0, 12582912LL, 1.f, 0, 6291456LL, 589824LL, 0, BIGN);
    gcn_epilogue_kernel<<<dim3(24576), dim3(256), 0, stream>>>(AXW0f, XW0f, W0b, DEN, OUT0);

    // ---- weight conversions (d_out free after AX; Z tails free) ----
    convert_planes_kernel<<<dim3(768), dim3(256), 0, stream>>>(Cw, CwP, 786432, 196608);
    pad_lw_kernel<<<dim3(2304), dim3(256), 0, stream>>>(Lw, LWPp);
    convert_qkw_kernel<<<dim3(4608), dim3(256), 0, stream>>>(Qw, Kw, QKwP);
    convert_planes_kernel<<<dim3(1152), dim3(256), 0, stream>>>(W1w, W1P, 1179648, 294912);

    // ---- phase 2: conv + linearc -> xcat planes ----
    gemm_mfma_kernel<2, 2, 1, 0><<<dim3(6, 4, 16), dim3(256), 0, stream>>>(
        CwP, OUT0, CONVEp, Cbi, 512, 768, 1536, 1536, 0, 768,
        0, 393216LL, 393216LL, 1.f, 1, 786432LL, 0, 6291456LL, 766);
    gemm_mfma_kernel<3, 3, 1, 0><<<dim3(6, 64, 1), dim3(256), 0, stream>>>(
        CONVEp, LWPp, (void*)(XCATp + 768), Lb, 8192, 768, 768, 768, 768, 1536,
        0, 0, 0, 1.f, 0, 6291456LL, 589824LL, 12582912LL, BIGN);
    copy_concat_kernel<<<dim3(24576), dim3(256), 0, stream>>>(inp, XCATp);

    // ---- phase 3: merged QK projection + scores per head ----
    for (int h = 0; h < 3; ++h) {
        gemm_mfma_kernel<4, 3, 1, 0><<<dim3(8, 64, 1), dim3(256), 0, stream>>>(
            XCATp, QKwP + (long long)h * 1572864, QKp, QKB + h * 1024,
            8192, 1024, 1536, 1536, 1536, 1024,
            0, 0, 0, 1.f, 0, 12582912LL, 4718592LL, 8388608LL, BIGN);
        gemm_mfma_kernel<5, 3, 0, 0><<<dim3(3, 4, 16), dim3(256), 0, stream>>>(
            QKp, QKp + 512, P + (long long)h * 196608, nullptr,
            512, 384, 512, 1024, 1024, 384,
            524288LL, 524288LL, 589824LL, divs, 0, 8388608LL, 8388608LL, 0, BIGN);
    }

    // ---- softmax + decisions ----
    softmax_kernel<<<dim3(24576), dim3(128), 0, stream>>>(P);
    sums1_kernel<<<dim3(768), dim3(256), 0, stream>>>(P, SUMP);
    decide2_kernel<<<dim3(1), dim3(64), 0, stream>>>(SUMP, MIDX);
    top2a_kernel<<<dim3(512), dim3(256), 0, stream>>>(P, MIDX, T2P);
    top2b_kernel<<<dim3(16), dim3(64), 0, stream>>>(T2P, THR);
    init_nnz_kernel<<<dim3(32), dim3(256), 0, stream>>>(CNT, NNZC, DEN2);
    scan_thr_kernel<<<dim3(192), dim3(256), 0, stream>>>(P, MIDX, THR, CNT, POS);
    build_nnz_kernel<<<dim3(1), dim3(64), 0, stream>>>(CNT, POS, NNZC, NNZJ, NNZV, DEN2);

    // ---- phase 5: GCN layer 1 (sparse adj2) + fc ----
    gemm_mfma_kernel<6, 3, 0, 0><<<dim3(6, 64, 1), dim3(256), 0, stream>>>(
        XCATp, W1P, XW1f, nullptr, 8192, 768, 1536, 1536, 1536, 768,
        0, 0, 0, 1.f, 0, 12582912LL, 1179648LL, 0, BIGN);
    convert_planes_kernel<<<dim3(576), dim3(256), 0, stream>>>(F1, F1P, 589824, 147456);
    convert_planes_kernel<<<dim3(576), dim3(256), 0, stream>>>(F2, F2P, 589824, 147456);
    gcn1_epilogue_kernel<<<dim3(8192), dim3(256), 0, stream>>>(XW1f, W1b, DEN2, NNZC, NNZJ, NNZV, OUTL1p);
    gemm_mfma_kernel<7, 3, 1, 0><<<dim3(6, 64, 1), dim3(256), 0, stream>>>(
        OUTL1p, F1P, H1p, nullptr, 8192, 768, 768, 768, 768, 768,
        0, 0, 0, 1.f, 1, 6291456LL, 589824LL, 6291456LL, BIGN);
    gemm_mfma_kernel<8, 3, 0, 0><<<dim3(6, 64, 1), dim3(256), 0, stream>>>(
        H1p, F2P, out, nullptr, 8192, 768, 768, 768, 768, 768,
        0, 0, 0, 1.f, 0, 6291456LL, 589824LL, 0, BIGN);
}

// Round 7
// 1119.122 us; speedup vs baseline: 8.0759x; 1.0273x over previous
//
#include <hip/hip_runtime.h>
#include <math.h>

// B=16, N=512, D=768, Dh=1536, HEADS=3, keys>=384 masked.
// GEMM core: 128x128 tile, 32x32x16 MFMA, BK=32, double-buffered LDS,
// SINGLE-BARRIER pipeline (round-7): per step
//   vmcnt(0) -> s_barrier -> stage(t+1) -> setprio(1) compute(t) setprio(0)
// Safety: stage at iter t+1 overwrites buffer computed at t-1; any wave there
// has passed barrier(t+1), which requires all waves finished compute(t).
// (r6 had TWO barriers/step; counters showed schedule-serialization: MfmaUtil
// 16.5 / VALU 26 / HBM 4.5% after coalescing+XCD-swizzle cut FETCH 210->25MB.)
// Staging: LDS rows [128][32] (64B); wave DMA covers 16 rows x full 64B
// (4 lanes/row, k-chunk XOR c^((row>>1)&3)); read slot = kc ^ ((lm>>1)&3).
// Bijective XCD-chunk blockIdx swizzle (T1/m204) for A-panel L2 reuse.
// bf16x2 hi/lo split (3-pass) for precision-critical GEMMs; AX (adj@inp) runs
// 1-pass bf16 (error /denom~257 -> ~3e-4), launch_bounds(256,3), 48KB LDS.
// 3-pass kernels launch_bounds(256,2) (r3 lesson: tighter caps spill acc).
//
// Arena (float units), 30539776 (~122.2 MB):
//  S [0,131072): scalars/lists (+QKB bias at 93184)
//  X [131072,+12582912): INPP planes (first half) + XW0f (second half) ->
//    OUT0 f32 -> XCATp planes -> F1P/F2P
//  Z = 12713984 (+17825792):
//   ph1: AXp[0,6.29M) AXW0f[6.29,12.58M) W0P[12.58,13.17M) ADJB[13.17,15.27M)
//   ph2: CONVEp[0,6.29M) CwP[6.29,7.08M) LWPp[7.08,7.67M)
//   ph3: QKp planes[0,8.39M) P f32[8.39,17.83M)
//   ph5: XW1f[0,6.29M) OUTL1p[6.29,12.58M) H1p[0,6.29M after XW1f dead)
//  d_out: ph1 INPTB bf16[0,3.15M); then QKwP[0,4.72M) W1P[4.72,5.9M); final out.

namespace {

constexpr long long O_DEN  = 0;
constexpr long long O_DEN2 = 8192;
constexpr long long O_SUMP = 16384;
constexpr long long O_THR  = 17920;
constexpr long long O_MIDX = 17936;
constexpr long long O_CNT  = 17952;
constexpr long long O_POS  = 17968;
constexpr long long O_T2P  = 18224;
constexpr long long O_NNZC = 19456;
constexpr long long O_NNZJ = 27648;
constexpr long long O_NNZV = 60416;
constexpr long long O_QKB  = 93184;   // 3072 floats

constexpr long long O_X    = 131072;
constexpr long long OZ     = 131072 + 12582912;          // 12713984
constexpr long long TOTAL_FLOATS = OZ + 17825792;        // 30539776

typedef short bf16x8 __attribute__((ext_vector_type(8)));
typedef float f32x4 __attribute__((ext_vector_type(4)));
typedef float f32x16 __attribute__((ext_vector_type(16)));

__global__ void sentinel_kernel(float* out) {
    if (threadIdx.x == 0 && blockIdx.x == 0) out[0] = 1.0e6f;
}

__device__ __forceinline__ unsigned short bf16rne(float f) {
    union { float x; unsigned u; } a; a.x = f;
    return (unsigned short)((a.u + 0x7FFFu + ((a.u >> 16) & 1u)) >> 16);
}

// RNE f32 -> bf16 hi + bf16(residual)
__device__ __forceinline__ void cvt_split(float f, unsigned short& h, unsigned short& l) {
    union { float x; unsigned u; } a; a.x = f;
    unsigned hb = (a.u + 0x7FFFu + ((a.u >> 16) & 1u)) & 0xFFFF0000u;
    h = (unsigned short)(hb >> 16);
    union { unsigned u; float x; } b; b.u = hb;
    float r = f - b.x;
    union { float x; unsigned u; } c; c.x = r;
    l = (unsigned short)((c.u + 0x7FFFu + ((c.u >> 16) & 1u)) >> 16);
}

// async 16B global->LDS (lds dest: wave-uniform base + lane*16)
__device__ __forceinline__ void gl_lds16(const unsigned short* g, unsigned short* l) {
    __builtin_amdgcn_global_load_lds(
        (const __attribute__((address_space(1))) unsigned int*)g,
        (__attribute__((address_space(3))) unsigned int*)l,
        16, 0, 0);
}

// ---------------- f32 -> planes converter ----------------
__global__ void convert_planes_kernel(const float* __restrict__ src, unsigned short* __restrict__ dst,
                                      long long loOff, long long n4) {
    long long idx = (long long)blockIdx.x * 256 + threadIdx.x;
    if (idx >= n4) return;
    float4 v = ((const float4*)src)[idx];
    unsigned short h0,h1,h2,h3,l0,l1,l2,l3;
    cvt_split(v.x,h0,l0); cvt_split(v.y,h1,l1); cvt_split(v.z,h2,l2); cvt_split(v.w,h3,l3);
    uint2 hp, lp;
    hp.x = (unsigned)h0 | ((unsigned)h1 << 16); hp.y = (unsigned)h2 | ((unsigned)h3 << 16);
    lp.x = (unsigned)l0 | ((unsigned)l1 << 16); lp.y = (unsigned)l2 | ((unsigned)l3 << 16);
    *(uint2*)&dst[idx * 4] = hp;
    *(uint2*)&dst[loOff + idx * 4] = lp;
}

// ---------------- f32 -> single bf16 plane ----------------
__global__ void convert_bf16_kernel(const float* __restrict__ src, unsigned short* __restrict__ dst,
                                    long long n4) {
    long long idx = (long long)blockIdx.x * 256 + threadIdx.x;
    if (idx >= n4) return;
    float4 v = ((const float4*)src)[idx];
    ushort4 o;
    o.x = bf16rne(v.x); o.y = bf16rne(v.y); o.z = bf16rne(v.z); o.w = bf16rne(v.w);
    *(ushort4*)&dst[idx * 4] = o;
}

// ------------- inp [z][512][768] f32 -> inp^T [z][768][512] bf16 -------------
__global__ void transpose_bf16_kernel(const float* __restrict__ inp, unsigned short* __restrict__ dst) {
    __shared__ float T[64][65];
    const int z = blockIdx.z;
    const int i0 = blockIdx.x * 64, d0 = blockIdx.y * 64;
    const float* src = inp + (long long)z * 393216;
    unsigned short* dz = dst + (long long)z * 393216;
    const int cl = threadIdx.x & 63, rl = threadIdx.x >> 6;
    #pragma unroll 4
    for (int e = 0; e < 16; ++e) {
        int il = e * 4 + rl;
        T[il][cl] = src[(long long)(i0 + il) * 768 + d0 + cl];
    }
    __syncthreads();
    #pragma unroll 4
    for (int e = 0; e < 16; ++e) {
        int dl = e * 4 + rl;
        dz[(long long)(d0 + dl) * 512 + i0 + cl] = bf16rne(T[cl][dl]);
    }
}

// ---------------- pad linearc_w [768,766] -> planes [768,768] ----------------
__global__ void pad_lw_kernel(const float* __restrict__ Lw, unsigned short* __restrict__ Lp) {
    int idx = blockIdx.x * 256 + threadIdx.x;  // 589824
    int n = idx / 768, k = idx - n * 768;
    float v = (k < 766) ? Lw[n * 766 + k] : 0.f;
    unsigned short h, l; cvt_split(v, h, l);
    Lp[idx] = h; Lp[589824 + idx] = l;
}

// ---------------- stacked QK weights -> planes [3][1024][1536] ----------------
__global__ void convert_qkw_kernel(const float* __restrict__ Qw, const float* __restrict__ Kw,
                                   unsigned short* __restrict__ dst) {
    long long idx = (long long)blockIdx.x * 256 + threadIdx.x;  // < 1179648
    if (idx >= 1179648) return;
    long long e = idx * 4;
    int h = (int)(e / 1572864);
    int rem = (int)(e - (long long)h * 1572864);
    int row = rem / 1536, k = rem - row * 1536;
    const float* src = (row < 512) ? (Qw + ((long long)(h * 512 + row) * 1536 + k))
                                   : (Kw + ((long long)(h * 512 + row - 512) * 1536 + k));
    float4 v = *(const float4*)src;
    unsigned short h0,h1,h2,h3,l0,l1,l2,l3;
    cvt_split(v.x,h0,l0); cvt_split(v.y,h1,l1); cvt_split(v.z,h2,l2); cvt_split(v.w,h3,l3);
    uint2 hp, lp;
    hp.x = (unsigned)h0 | ((unsigned)h1 << 16); hp.y = (unsigned)h2 | ((unsigned)h3 << 16);
    lp.x = (unsigned)l0 | ((unsigned)l1 << 16); lp.y = (unsigned)l2 | ((unsigned)l3 << 16);
    *(uint2*)&dst[e] = hp;
    *(uint2*)&dst[4718592 + e] = lp;
}

// ---------------- stacked QK bias [3][1024] ----------------
__global__ void qkb_kernel(const float* __restrict__ Qb, const float* __restrict__ Kb,
                           float* __restrict__ qkb) {
    int i = blockIdx.x * 256 + threadIdx.x;
    if (i >= 3072) return;
    int h = i >> 10, r = i & 1023;
    qkb[i] = (r < 512) ? Qb[h * 512 + r] : Kb[h * 512 + r - 512];
}

// ===== MFMA GEMM, 128x128 tile, 32x32x16, BK=32, single-barrier pipeline =====
// A: always bf16 planes, async (lo at +aLo; ONEPASS -> hi only).
// BMODE: 3=NT planes async, 2=conv f32 window (bias by m; VALU-staged B).
// CMODE: 0=f32, 1=planes (lo at +cLo). n>=Nreal -> 0.
// LDS tile [128][32] ushort (64B rows). Swizzle: LDS[row][slot c] holds global
// k-chunk (c ^ ((row>>1)&3)); read slot = kc ^ ((lm>>1)&3).
template<int TAG, int BMODE, int CMODE, int ONEPASS>
__global__ __launch_bounds__(256, ONEPASS ? 3 : 2)
void gemm_mfma_kernel(const unsigned short* __restrict__ Au, const void* __restrict__ Bv,
                      void* __restrict__ Cv, const float* __restrict__ bias,
                      int M, int N, int K, int lda, int ldb, int ldc,
                      long long sA, long long sB, long long sC,
                      float divd, int relu, long long aLo,
                      long long bLo, long long cLo, int Nreal)
{
    __shared__ __align__(16) unsigned short AhS[2][128][32];
    __shared__ __align__(16) unsigned short BhS[2][128][32];
    __shared__ __align__(16) unsigned short AlS[ONEPASS ? 1 : 2][128][32];
    __shared__ __align__(16) unsigned short BlS[ONEPASS ? 1 : 2][128][32];

    // ---- bijective XCD-chunk swizzle (T1/m204) ----
    const int gx = gridDim.x, gy = gridDim.y;
    const int nwg = gx * gy * gridDim.z;
    const int lin = blockIdx.x + gx * (blockIdx.y + gy * blockIdx.z);
    const int q8 = nwg >> 3, r8 = nwg & 7;
    const int xcd = lin & 7, sidx = lin >> 3;
    const int nl = (xcd < r8) ? xcd * (q8 + 1) + sidx : r8 * (q8 + 1) + (xcd - r8) * q8 + sidx;
    const int bx = nl % gx;
    const int t1 = nl / gx;
    const int by = t1 % gy;
    const int z  = t1 / gy;

    const int tid = threadIdx.x;
    const int m0 = by * 128, n0 = bx * 128;
    const int lane = tid & 63, wave = tid >> 6;
    const int wm = (wave & 1) * 64, wn = (wave >> 1) * 64;
    const int lk = lane >> 5, lm = lane & 31;
    const int sxor = (lm >> 1) & 3;                 // read-side slot XOR

    const unsigned short* A = Au + z * sA;
    const float* Bf = (const float*)Bv + z * sB;
    const unsigned short* Bu = (const unsigned short*)Bv + z * sB;
    float* Cf = (float*)Cv + z * sC;
    unsigned short* Cu = (unsigned short*)Cv + z * sC;

    f32x16 acc[2][2];
    #pragma unroll
    for (int i = 0; i < 2; ++i)
        #pragma unroll
        for (int j = 0; j < 2; ++j)
            #pragma unroll
            for (int r = 0; r < 16; ++r) acc[i][j][r] = 0.f;

    // staging map: chunk index j = v*256 + wave*64 + lane; row=j>>2, c=j&3.
    // source k-chunk = c ^ ((row>>1)&3); per-row 4 lanes cover full 64B line.
    auto stage = [&](int kk, int b) {
        #pragma unroll
        for (int v = 0; v < 2; ++v) {
            const int j0 = v * 256 + (wave << 6);   // uniform chunk base
            const int row0 = j0 >> 2;               // uniform LDS row base
            const int j = j0 + lane;
            const int row = j >> 2, c = j & 3;
            const int kch = c ^ ((row >> 1) & 3);
            const long long aoff = (long long)(m0 + row) * lda + kk + kch * 8;
            gl_lds16(A + aoff, &AhS[b][row0][0]);
            if constexpr (!ONEPASS) gl_lds16(A + aLo + aoff, &AlS[b][row0][0]);
            if constexpr (BMODE == 3) {
                const long long boff = (long long)(n0 + row) * ldb + kk + kch * 8;
                gl_lds16(Bu + boff, &BhS[b][row0][0]);
                if constexpr (!ONEPASS) gl_lds16(Bu + bLo + boff, &BlS[b][row0][0]);
            }
        }
        if constexpr (BMODE == 2) {
            // conv window B: VALU-staged, linear 16B ds_writes (conflict-free).
            #pragma unroll
            for (int v = 0; v < 2; ++v) {
                const int j = v * 256 + tid;
                const int n = j >> 2, c = j & 3;
                const int kch = c ^ ((n >> 1) & 3);
                const int k8 = kk + kch * 8;
                unsigned short hh[8], ll[8];
                #pragma unroll
                for (int e = 0; e < 8; ++e) {
                    const int kg = k8 + e;
                    const int ii = kg / 3, k3 = kg - ii * 3;
                    // edge cols >=768 read into next row; only feed C cols >=Nreal (zeroed)
                    cvt_split(Bf[(long long)ii * 768 + (n0 + n) + k3], hh[e], ll[e]);
                }
                uint4 hp, lp;
                hp.x = (unsigned)hh[0] | ((unsigned)hh[1] << 16);
                hp.y = (unsigned)hh[2] | ((unsigned)hh[3] << 16);
                hp.z = (unsigned)hh[4] | ((unsigned)hh[5] << 16);
                hp.w = (unsigned)hh[6] | ((unsigned)hh[7] << 16);
                lp.x = (unsigned)ll[0] | ((unsigned)ll[1] << 16);
                lp.y = (unsigned)ll[2] | ((unsigned)ll[3] << 16);
                lp.z = (unsigned)ll[4] | ((unsigned)ll[5] << 16);
                lp.w = (unsigned)ll[6] | ((unsigned)ll[7] << 16);
                *(uint4*)&BhS[b][n][c * 8] = hp;
                *(uint4*)&BlS[b][n][c * 8] = lp;
            }
        }
    };

    auto compute = [&](int b) {
        #pragma unroll
        for (int ks = 0; ks < 2; ++ks) {
            const int kc = ks * 2 + lk;
            const int sl = (kc ^ sxor) * 8;
            bf16x8 ah[2], bh[2];
            #pragma unroll
            for (int i = 0; i < 2; ++i) ah[i] = *(const bf16x8*)&AhS[b][wm + i * 32 + lm][sl];
            #pragma unroll
            for (int j = 0; j < 2; ++j) bh[j] = *(const bf16x8*)&BhS[b][wn + j * 32 + lm][sl];
            if constexpr (ONEPASS) {
                #pragma unroll
                for (int i = 0; i < 2; ++i)
                    #pragma unroll
                    for (int j = 0; j < 2; ++j)
                        acc[i][j] = __builtin_amdgcn_mfma_f32_32x32x16_bf16(ah[i], bh[j], acc[i][j], 0, 0, 0);
            } else {
                bf16x8 al[2], bl[2];
                #pragma unroll
                for (int i = 0; i < 2; ++i) al[i] = *(const bf16x8*)&AlS[b][wm + i * 32 + lm][sl];
                #pragma unroll
                for (int j = 0; j < 2; ++j) bl[j] = *(const bf16x8*)&BlS[b][wn + j * 32 + lm][sl];
                #pragma unroll
                for (int i = 0; i < 2; ++i)
                    #pragma unroll
                    for (int j = 0; j < 2; ++j) {
                        acc[i][j] = __builtin_amdgcn_mfma_f32_32x32x16_bf16(ah[i], bh[j], acc[i][j], 0, 0, 0);
                        acc[i][j] = __builtin_amdgcn_mfma_f32_32x32x16_bf16(ah[i], bl[j], acc[i][j], 0, 0, 0);
                        acc[i][j] = __builtin_amdgcn_mfma_f32_32x32x16_bf16(al[i], bh[j], acc[i][j], 0, 0, 0);
                    }
            }
        }
    };

    const int nt = K >> 5;
    // ---- single-barrier pipeline (both modes) ----
    // iter t: wait stage(t) -> barrier -> stage(t+1, b^1) -> compute(t, b).
    // stage at iter t+1 overwrites buffer computed at t-1; reaching it requires
    // passing barrier(t+1), which requires all waves done with compute(t).
    stage(0, 0);
    for (int t = 0; t < nt; ++t) {
        if constexpr (BMODE == 2) {
            asm volatile("s_waitcnt vmcnt(0) lgkmcnt(0)" ::: "memory");
        } else {
            asm volatile("s_waitcnt vmcnt(0)" ::: "memory");
        }
        __builtin_amdgcn_sched_barrier(0);
        __builtin_amdgcn_s_barrier();     // all waves' stage(t) visible
        __builtin_amdgcn_sched_barrier(0);
        if (t + 1 < nt) stage((t + 1) << 5, (t + 1) & 1);
        __builtin_amdgcn_s_setprio(1);
        compute(t & 1);
        __builtin_amdgcn_s_setprio(0);
    }
    // ---- epilogue: C/D layout col=lane&31, row=(reg&3)+8*(reg>>2)+4*(lane>>5) ----
    #pragma unroll
    for (int i = 0; i < 2; ++i) {
        #pragma unroll
        for (int j = 0; j < 2; ++j) {
            #pragma unroll
            for (int reg = 0; reg < 16; ++reg) {
                const int m = m0 + wm + i * 32 + (reg & 3) + 8 * (reg >> 2) + 4 * lk;
                const int n = n0 + wn + j * 32 + lm;
                float v = acc[i][j][reg];
                if (divd != 1.f) v = v / divd;
                if (bias) v += bias[BMODE == 2 ? m : n];
                if (relu) v = fmaxf(v, 0.f);
                if (n >= Nreal) v = 0.f;
                if constexpr (CMODE == 1) {
                    unsigned short h, l; cvt_split(v, h, l);
                    Cu[(long long)m * ldc + n] = h;
                    Cu[cLo + (long long)m * ldc + n] = l;
                } else {
                    Cf[(long long)m * ldc + n] = v;
                }
            }
        }
    }
}

// ---------------- row sum (+1) for adj ----------------
__global__ void rowsum_kernel(const float* __restrict__ A, float* __restrict__ out, int ncols) {
    const float* row = A + (long long)blockIdx.x * ncols;
    float s = 0.f;
    for (int j = threadIdx.x; j < ncols; j += 256) s += row[j];
    __shared__ float red[256];
    red[threadIdx.x] = s;
    __syncthreads();
    for (int st = 128; st > 0; st >>= 1) {
        if (threadIdx.x < st) red[threadIdx.x] += red[threadIdx.x + st];
        __syncthreads();
    }
    if (threadIdx.x == 0) out[blockIdx.x] = red[0] + 1.0f;
}

// ------------- GCN layer-0 epilogue -------------
__global__ void gcn_epilogue_kernel(const float* __restrict__ axw, const float* __restrict__ xw,
                                    const float* __restrict__ bias, const float* __restrict__ denom,
                                    float* __restrict__ out)
{
    long long idx = (long long)blockIdx.x * 256 + threadIdx.x;  // 8192*768
    int m = (int)(idx / 768);
    int d = (int)(idx - (long long)m * 768);
    float bb = bias[d];
    float v = (axw[idx] + bb) / denom[m];
    out[idx] = fmaxf(v, 0.f) + xw[idx] + bb;
}

// ------------- inputs -> XCAT planes cols 0..767 -------------
__global__ void copy_concat_kernel(const float* __restrict__ inp, unsigned short* __restrict__ xcat)
{
    long long idx = (long long)blockIdx.x * 256 + threadIdx.x;  // 8192*768
    int m = (int)(idx / 768);
    int d = (int)(idx - (long long)m * 768);
    unsigned short h, l; cvt_split(inp[idx], h, l);
    xcat[(long long)m * 1536 + d] = h;
    xcat[12582912LL + (long long)m * 1536 + d] = l;
}

// ------------- row softmax over 384 stored cols (ld=384) -------------
__global__ void softmax_kernel(float* __restrict__ P)
{
    float* row = P + (long long)blockIdx.x * 384;
    const int t = threadIdx.x;  // 128
    float v0 = row[t], v1 = row[t + 128], v2 = row[t + 256];
    float m = fmaxf(v0, fmaxf(v1, v2));
    #pragma unroll
    for (int off = 32; off > 0; off >>= 1) m = fmaxf(m, __shfl_down(m, off));
    __shared__ float redm[2];
    if ((t & 63) == 0) redm[t >> 6] = m;
    __syncthreads();
    m = fmaxf(redm[0], redm[1]);
    float e0 = expf(v0 - m), e1 = expf(v1 - m), e2 = expf(v2 - m);
    float s = e0 + e1 + e2;
    #pragma unroll
    for (int off = 32; off > 0; off >>= 1) s += __shfl_down(s, off);
    __shared__ float reds[2];
    if ((t & 63) == 0) reds[t >> 6] = s;
    __syncthreads();
    s = reds[0] + reds[1];
    row[t] = e0 / s;
    row[t + 128] = e1 / s;
    row[t + 256] = e2 / s;
}

// ------------- sums stage 1 (f64 partials) -------------
__global__ void sums1_kernel(const float* __restrict__ P, double* __restrict__ sump)
{
    int blk = blockIdx.x;
    int bh = blk >> 4, ch = blk & 15;
    const float* p = P + (long long)bh * 196608 + ch * 12288;
    double s = 0.0;
    for (int i = threadIdx.x; i < 12288; i += 256) s += (double)p[i];
    __shared__ double red[256];
    red[threadIdx.x] = s;
    __syncthreads();
    for (int st = 128; st > 0; st >>= 1) {
        if (threadIdx.x < st) red[threadIdx.x] += red[threadIdx.x + st];
        __syncthreads();
    }
    if (threadIdx.x == 0) sump[blk] = red[0];
}

// ------------- sums stage 2 + head decision -------------
__global__ void decide2_kernel(const double* __restrict__ sump, int* __restrict__ maxidx)
{
    __shared__ double s48[48];
    int t = threadIdx.x;
    if (t < 48) {
        double s = 0.0;
        for (int i = 0; i < 16; ++i) s += sump[t * 16 + i];
        s48[t] = s;
    }
    __syncthreads();
    if (t == 0) {
        float s[16][3], prob[16][3];
        for (int b = 0; b < 16; ++b)
            for (int h = 0; h < 3; ++h) s[b][h] = (float)s48[b * 3 + h];
        for (int h = 0; h < 3; ++h) {
            float m = -1e30f;
            for (int b = 0; b < 16; ++b) m = fmaxf(m, s[b][h]);
            float e[16]; float Z = 0.f;
            for (int b = 0; b < 16; ++b) { e[b] = expf(s[b][h] - m); Z += e[b]; }
            for (int b = 0; b < 16; ++b) prob[b][h] = e[b] / Z;
        }
        for (int b = 0; b < 16; ++b) {
            int best = 0; float bv = prob[b][0];
            for (int h = 1; h < 3; ++h) if (prob[b][h] > bv) { bv = prob[b][h]; best = h; }
            maxidx[b] = best;
        }
    }
}

// ------------- top2 stage 1 -------------
__global__ void top2a_kernel(const float* __restrict__ P, const int* __restrict__ maxidx,
                             float2* __restrict__ t2p)
{
    int blk = blockIdx.x;
    int b = blk >> 5, ch = blk & 31;
    const float* p = P + ((long long)b * 3 + maxidx[b]) * 196608 + ch * 6144;
    float m1 = -1e30f, m2 = -1e30f;
    for (int i = threadIdx.x; i < 6144; i += 256) {
        float v = p[i];
        if (v > m1) { m2 = m1; m1 = v; }
        else if (v > m2) { m2 = v; }
    }
    __shared__ float r1[256], r2[256];
    r1[threadIdx.x] = m1; r2[threadIdx.x] = m2;
    __syncthreads();
    if (threadIdx.x == 0) {
        float M1 = -1e30f, M2 = -1e30f;
        for (int i = 0; i < 256; ++i) {
            float a = r1[i], c = r2[i];
            if (a > M1) { M2 = M1; M1 = a; } else if (a > M2) { M2 = a; }
            if (c > M1) { M2 = M1; M1 = c; } else if (c > M2) { M2 = c; }
        }
        t2p[blk] = make_float2(M1, M2);
    }
}

// ------------- top2 stage 2 -------------
__global__ void top2b_kernel(const float2* __restrict__ t2p, float* __restrict__ thr)
{
    int b = blockIdx.x;
    if (threadIdx.x != 0) return;
    float M1 = -1e30f, M2 = -1e30f;
    for (int i = 0; i < 32; ++i) {
        float2 v = t2p[b * 32 + i];
        if (v.x > M1) { M2 = M1; M1 = v.x; } else if (v.x > M2) { M2 = v.x; }
        if (v.y > M1) { M2 = M1; M1 = v.y; } else if (v.y > M2) { M2 = v.y; }
    }
    thr[b] = M2;
}

// ------------- init nnz state -------------
__global__ void init_nnz_kernel(int* __restrict__ cntb, int* __restrict__ nnzc,
                                float* __restrict__ den2)
{
    int idx = blockIdx.x * 256 + threadIdx.x;
    if (idx < 16) cntb[idx] = 0;
    if (idx < 8192) { nnzc[idx] = 0; den2[idx] = 1.f; }
}

// ------------- scan P for p>=thr (exact >= tie semantics) -------------
__global__ void scan_thr_kernel(const float* __restrict__ P, const int* __restrict__ maxidx,
                                const float* __restrict__ thr, int* __restrict__ cntb,
                                int* __restrict__ pos)
{
    int blk = blockIdx.x;            // 16*12
    int b = blk / 12, ch = blk % 12;
    const float* p = P + ((long long)b * 3 + maxidx[b]) * 196608;
    float t = thr[b];
    int base = ch * 16384;
    for (int l = 0; l < 64; ++l) {
        int idx = base + threadIdx.x + l * 256;
        if (p[idx] >= t) {
            int q = atomicAdd(&cntb[b], 1);
            if (q < 16) {
                int i = idx / 384, j = idx - i * 384;
                pos[b * 16 + q] = (i << 16) | j;
            }
        }
    }
}

// ------------- build nnz lists + den2 -------------
__global__ void build_nnz_kernel(const int* __restrict__ cntb, const int* __restrict__ pos,
                                 int* __restrict__ nnzc, int* __restrict__ jn,
                                 float* __restrict__ jv, float* __restrict__ den2)
{
    int b = threadIdx.x;
    if (b >= 16 || blockIdx.x != 0) return;
    int c = cntb[b]; if (c > 16) c = 16;
    for (int e = 0; e < c; ++e) {
        int pk = pos[b * 16 + e];
        int i = pk >> 16, j = pk & 0xFFFF;
        float val;
        if (i == j) val = 1.f;
        else {
            int rev = (j << 16) | i;
            int found = 0;
            for (int e2 = 0; e2 < c; ++e2) if (pos[b * 16 + e2] == rev) found = 1;
            val = 1.f + (float)found;
        }
        int r = b * 512 + i;
        int slot = nnzc[r];
        if (slot < 4) { jn[r * 4 + slot] = b * 512 + j; jv[r * 4 + slot] = val; }
        nnzc[r] = slot + 1;
        den2[r] += val;
    }
}

// ------------- GCN layer-1 fused sparse epilogue -> OUTL1 planes -------------
__global__ void gcn1_epilogue_kernel(const float* __restrict__ XW1, const float* __restrict__ b1,
                                     const float* __restrict__ den2, const int* __restrict__ cnt,
                                     const int* __restrict__ jn, const float* __restrict__ jv,
                                     unsigned short* __restrict__ outp)
{
    int m = blockIdx.x;
    int c = cnt[m]; if (c > 4) c = 4;
    float d2 = den2[m];
    int js[4]; float vs[4];
    for (int s = 0; s < c; ++s) { js[s] = jn[m * 4 + s]; vs[s] = jv[m * 4 + s]; }
    const float* xrow = XW1 + (long long)m * 768;
    #pragma unroll
    for (int l = 0; l < 3; ++l) {
        int d = threadIdx.x + l * 256;
        float ax = 0.f;
        for (int s = 0; s < c; ++s) ax += vs[s] * XW1[(long long)js[s] * 768 + d];
        float bb = b1[d];
        float v = fmaxf((ax + bb) / d2, 0.f) + xrow[d] + bb;
        unsigned short h, lo; cvt_split(v, h, lo);
        outp[(long long)m * 768 + d] = h;
        outp[6291456LL + (long long)m * 768 + d] = lo;
    }
}

}  // namespace

extern "C" void kernel_launch(void* const* d_in, const int* in_sizes, int n_in,
                              void* d_out, int out_size, void* d_ws, size_t ws_size,
                              hipStream_t stream) {
    const float* adj = (const float*)d_in[0];
    const float* inp = (const float*)d_in[1];
    const float* W0w = (const float*)d_in[3];
    const float* W0b = (const float*)d_in[4];
    const float* W1w = (const float*)d_in[5];
    const float* W1b = (const float*)d_in[6];
    const float* Cw  = (const float*)d_in[7];
    const float* Cbi = (const float*)d_in[8];
    const float* Lw  = (const float*)d_in[9];
    const float* Lb  = (const float*)d_in[10];
    const float* F1  = (const float*)d_in[11];
    const float* F2  = (const float*)d_in[12];
    const float* Qw  = (const float*)d_in[13];
    const float* Qb  = (const float*)d_in[14];
    const float* Kw  = (const float*)d_in[15];
    const float* Kbi = (const float*)d_in[16];
    float* out = (float*)d_out;

    if (ws_size < (size_t)TOTAL_FLOATS * sizeof(float)) {
        sentinel_kernel<<<dim3(1), dim3(64), 0, stream>>>(out);
        return;
    }

    float* W = (float*)d_ws;
    float*   DEN   = W + O_DEN;
    float*   DEN2  = W + O_DEN2;
    double*  SUMP  = (double*)(W + O_SUMP);
    float*   THR   = W + O_THR;
    int*     MIDX  = (int*)(W + O_MIDX);
    int*     CNT   = (int*)(W + O_CNT);
    int*     POS   = (int*)(W + O_POS);
    float2*  T2P   = (float2*)(W + O_T2P);
    int*     NNZC  = (int*)(W + O_NNZC);
    int*     NNZJ  = (int*)(W + O_NNZJ);
    float*   NNZV  = W + O_NNZV;
    float*   QKB   = W + O_QKB;

    unsigned short* INPP  = (unsigned short*)(W + O_X);
    float*          OUT0  = W + O_X;
    unsigned short* XCATp = (unsigned short*)(W + O_X);
    unsigned short* F1P   = (unsigned short*)(W + O_X);
    unsigned short* F2P   = (unsigned short*)(W + O_X + 589824);

    unsigned short* AXp    = (unsigned short*)(W + OZ);
    float*          AXW0f  = W + OZ + 6291456;
    float*          XW0f   = W + O_X + 6291456;           // X-region second half
    unsigned short* W0P    = (unsigned short*)(W + OZ + 12582912);
    unsigned short* ADJB   = (unsigned short*)(W + OZ + 13172736);
    unsigned short* CONVEp = (unsigned short*)(W + OZ);
    unsigned short* CwP    = (unsigned short*)(W + OZ + 6291456);
    unsigned short* LWPp   = (unsigned short*)(W + OZ + 7077888);
    unsigned short* QKp    = (unsigned short*)(W + OZ);
    float*          P      = W + OZ + 8388608;
    float*          XW1f   = W + OZ;
    unsigned short* OUTL1p = (unsigned short*)(W + OZ + 6291456);
    unsigned short* H1p    = (unsigned short*)(W + OZ);

    unsigned short* INPTB  = (unsigned short*)out;         // ph1 only
    unsigned short* QKwP   = (unsigned short*)out;
    unsigned short* W1P    = (unsigned short*)(out + 4718592);

    const float divs = sqrtf(512.0f);
    const int BIGN = 1 << 30;

    // ---- phase 1: GCN layer 0 ----
    convert_planes_kernel<<<dim3(6144), dim3(256), 0, stream>>>(inp, INPP, 6291456, 1572864);
    convert_planes_kernel<<<dim3(576), dim3(256), 0, stream>>>(W0w, W0P, 589824, 147456);
    convert_bf16_kernel<<<dim3(4096), dim3(256), 0, stream>>>(adj, ADJB, 1048576);
    transpose_bf16_kernel<<<dim3(8, 12, 16), dim3(256), 0, stream>>>(inp, INPTB);
    qkb_kernel<<<dim3(12), dim3(256), 0, stream>>>(Qb, Kbi, QKB);
    rowsum_kernel<<<dim3(8192), dim3(256), 0, stream>>>(adj, DEN, 512);
    // AX = adj @ inputs -> planes (1-pass bf16: error /denom(~257) ~3e-4)
    gemm_mfma_kernel<0, 3, 1, 1><<<dim3(6, 4, 16), dim3(256), 0, stream>>>(
        ADJB, INPTB, AXp, nullptr, 512, 768, 512, 512, 512, 768,
        262144LL, 393216LL, 393216LL, 1.f, 0, 0, 0, 6291456LL, BIGN);
    // XW0 = inp @ W0^T (z=0) and AXW0 = AX @ W0^T (z=1), merged via z-strides
    gemm_mfma_kernel<1, 3, 0, 0><<<dim3(6, 64, 2), dim3(256), 0, stream>>>(
        INPP, W0P, XW0f, nullptr, 8192, 768, 768, 768, 768, 768,
        25165824LL, 0, 12582912LL, 1.f, 0, 6291456LL, 589824LL, 0, BIGN);
    gcn_epilogue_kernel<<<dim3(24576), dim3(256), 0, stream>>>(AXW0f, XW0f, W0b, DEN, OUT0);

    // ---- weight conversions (d_out free after AX; Z tails free) ----
    convert_planes_kernel<<<dim3(768), dim3(256), 0, stream>>>(Cw, CwP, 786432, 196608);
    pad_lw_kernel<<<dim3(2304), dim3(256), 0, stream>>>(Lw, LWPp);
    convert_qkw_kernel<<<dim3(4608), dim3(256), 0, stream>>>(Qw, Kw, QKwP);
    convert_planes_kernel<<<dim3(1152), dim3(256), 0, stream>>>(W1w, W1P, 1179648, 294912);

    // ---- phase 2: conv + linearc -> xcat planes ----
    gemm_mfma_kernel<2, 2, 1, 0><<<dim3(6, 4, 16), dim3(256), 0, stream>>>(
        CwP, OUT0, CONVEp, Cbi, 512, 768, 1536, 1536, 0, 768,
        0, 393216LL, 393216LL, 1.f, 1, 786432LL, 0, 6291456LL, 766);
    gemm_mfma_kernel<3, 3, 1, 0><<<dim3(6, 64, 1), dim3(256), 0, stream>>>(
        CONVEp, LWPp, (void*)(XCATp + 768), Lb, 8192, 768, 768, 768, 768, 1536,
        0, 0, 0, 1.f, 0, 6291456LL, 589824LL, 12582912LL, BIGN);
    copy_concat_kernel<<<dim3(24576), dim3(256), 0, stream>>>(inp, XCATp);

    // ---- phase 3: merged QK projection + scores per head ----
    for (int h = 0; h < 3; ++h) {
        gemm_mfma_kernel<4, 3, 1, 0><<<dim3(8, 64, 1), dim3(256), 0, stream>>>(
            XCATp, QKwP + (long long)h * 1572864, QKp, QKB + h * 1024,
            8192, 1024, 1536, 1536, 1536, 1024,
            0, 0, 0, 1.f, 0, 12582912LL, 4718592LL, 8388608LL, BIGN);
        gemm_mfma_kernel<5, 3, 0, 0><<<dim3(3, 4, 16), dim3(256), 0, stream>>>(
            QKp, QKp + 512, P + (long long)h * 196608, nullptr,
            512, 384, 512, 1024, 1024, 384,
            524288LL, 524288LL, 589824LL, divs, 0, 8388608LL, 8388608LL, 0, BIGN);
    }

    // ---- softmax + decisions ----
    softmax_kernel<<<dim3(24576), dim3(128), 0, stream>>>(P);
    sums1_kernel<<<dim3(768), dim3(256), 0, stream>>>(P, SUMP);
    decide2_kernel<<<dim3(1), dim3(64), 0, stream>>>(SUMP, MIDX);
    top2a_kernel<<<dim3(512), dim3(256), 0, stream>>>(P, MIDX, T2P);
    top2b_kernel<<<dim3(16), dim3(64), 0, stream>>>(T2P, THR);
    init_nnz_kernel<<<dim3(32), dim3(256), 0, stream>>>(CNT, NNZC, DEN2);
    scan_thr_kernel<<<dim3(192), dim3(256), 0, stream>>>(P, MIDX, THR, CNT, POS);
    build_nnz_kernel<<<dim3(1), dim3(64), 0, stream>>>(CNT, POS, NNZC, NNZJ, NNZV, DEN2);

    // ---- phase 5: GCN layer 1 (sparse adj2) + fc ----
    gemm_mfma_kernel<6, 3, 0, 0><<<dim3(6, 64, 1), dim3(256), 0, stream>>>(
        XCATp, W1P, XW1f, nullptr, 8192, 768, 1536, 1536, 1536, 768,
        0, 0, 0, 1.f, 0, 12582912LL, 1179648LL, 0, BIGN);
    convert_planes_kernel<<<dim3(576), dim3(256), 0, stream>>>(F1, F1P, 589824, 147456);
    convert_planes_kernel<<<dim3(576), dim3(256), 0, stream>>>(F2, F2P, 589824, 147456);
    gcn1_epilogue_kernel<<<dim3(8192), dim3(256), 0, stream>>>(XW1f, W1b, DEN2, NNZC, NNZJ, NNZV, OUTL1p);
    gemm_mfma_kernel<7, 3, 1, 0><<<dim3(6, 64, 1), dim3(256), 0, stream>>>(
        OUTL1p, F1P, H1p, nullptr, 8192, 768, 768, 768, 768, 768,
        0, 0, 0, 1.f, 1, 6291456LL, 589824LL, 6291456LL, BIGN);
    gemm_mfma_kernel<8, 3, 0, 0><<<dim3(6, 64, 1), dim3(256), 0, stream>>>(
        H1p, F2P, out, nullptr, 8192, 768, 768, 768, 768, 768,
        0, 0, 0, 1.f, 0, 6291456LL, 589824LL, 0, BIGN);
}